// Round 6
// baseline (205.582 us; speedup 1.0000x reference)
//
#include <hip/hip_runtime.h>
#include <math.h>

#define NN 100000
#define NE 1600000
#define DIN 256
#define DHID 128
#define NCLS 64
#define NEG_SLOPE 0.2f

#define NBUCK 196          // ceil(NN / 512), bucket = dst >> 9
#define CHUNK 4096
#define NCHB ((NE + CHUNK - 1) / CHUNK)   // 391

typedef __bf16 bf16_t;
typedef bf16_t bf16x8 __attribute__((ext_vector_type(8)));
typedef float f32x4 __attribute__((ext_vector_type(4)));
typedef ushort ushort8v __attribute__((ext_vector_type(8)));

__device__ __forceinline__ ushort f2bf(float f) {
    union { float f; unsigned u; } c; c.f = f;
    unsigned u = c.u;
    unsigned r = (u + 0x7FFFu + ((u >> 16) & 1u)) >> 16;
    return (ushort)r;
}
__device__ __forceinline__ float bf2f(ushort b) {
    return __uint_as_float(((unsigned)b) << 16);
}

// ================= CSR build: bucketed counting sort =================
__global__ __launch_bounds__(256) void k_ghist(const int* __restrict__ dst,
                                               int* __restrict__ ghist) {
    __shared__ int h[NBUCK];
    int t = threadIdx.x;
    for (int i = t; i < NBUCK; i += 256) h[i] = 0;
    __syncthreads();
    int base = blockIdx.x * CHUNK;
    int end = base + CHUNK; if (end > NE) end = NE;
    for (int idx = base + t; idx < end; idx += 256)
        atomicAdd(&h[dst[idx] >> 9], 1);
    __syncthreads();
    for (int i = t; i < NBUCK; i += 256)
        if (h[i]) atomicAdd(&ghist[i], h[i]);
}

__global__ __launch_bounds__(256) void k_gscan(const int* __restrict__ ghist,
                                               int* __restrict__ boff,
                                               int* __restrict__ gcur) {
    __shared__ int sh[256];
    int t = threadIdx.x;
    int v = (t < NBUCK) ? ghist[t] : 0;
    sh[t] = v;
    __syncthreads();
    for (int d = 1; d < 256; d <<= 1) {
        int a = (t >= d) ? sh[t - d] : 0;
        __syncthreads();
        sh[t] += a;
        __syncthreads();
    }
    if (t < NBUCK) {
        int ex = sh[t] - v;
        boff[t] = ex;
        gcur[t] = ex;
        if (t == NBUCK - 1) boff[NBUCK] = sh[t];
    }
}

__global__ __launch_bounds__(256) void k_bin(const int* __restrict__ src,
                                             const int* __restrict__ dst,
                                             int* __restrict__ gcur,
                                             unsigned* __restrict__ ebuf) {
    __shared__ int hist[NBUCK];
    __shared__ int scn[256];
    __shared__ int loff[NBUCK];
    __shared__ int cur[NBUCK];
    __shared__ int gb[NBUCK];
    __shared__ unsigned ord[CHUNK];
    __shared__ ushort obk[CHUNK];
    const int t = threadIdx.x;
    const int base = blockIdx.x * CHUNK;
    int cnt = NE - base; if (cnt > CHUNK) cnt = CHUNK;

    for (int i = t; i < NBUCK; i += 256) hist[i] = 0;
    __syncthreads();

    unsigned vals[16];
    int bks[16];
#pragma unroll
    for (int i = 0; i < 16; i++) {
        int idx = base + i * 256 + t;
        if (idx < NE) {
            int d = dst[idx], s = src[idx];
            int bb = d >> 9;
            bks[i] = bb;
            vals[i] = ((unsigned)(d & 511) << 17) | (unsigned)s;
            atomicAdd(&hist[bb], 1);
        } else bks[i] = -1;
    }
    __syncthreads();

    int hv = (t < NBUCK) ? hist[t] : 0;
    scn[t] = hv;
    __syncthreads();
    for (int d = 1; d < 256; d <<= 1) {
        int a = (t >= d) ? scn[t - d] : 0;
        __syncthreads();
        scn[t] += a;
        __syncthreads();
    }
    if (t < NBUCK) { loff[t] = scn[t] - hv; cur[t] = scn[t] - hv; }
    __syncthreads();

#pragma unroll
    for (int i = 0; i < 16; i++) {
        if (bks[i] >= 0) {
            int slot = atomicAdd(&cur[bks[i]], 1);
            ord[slot] = vals[i];
            obk[slot] = (ushort)bks[i];
        }
    }
    if (t < NBUCK && hv > 0) gb[t] = atomicAdd(&gcur[t], hv);
    __syncthreads();

    for (int s = t; s < cnt; s += 256) {
        int bb = obk[s];
        ebuf[gb[bb] + (s - loff[bb])] = ord[s];
    }
}

__global__ __launch_bounds__(256) void k_csr(const unsigned* __restrict__ ebuf,
                                             const int* __restrict__ boff,
                                             int* __restrict__ off_g,
                                             int* __restrict__ deg_g,
                                             int* __restrict__ ssrc) {
    __shared__ int sdeg[512];
    __shared__ int pr[256];
    __shared__ int lofs[512];
    __shared__ int scnt[512];
    const int b = blockIdx.x, t = threadIdx.x;
    const int node0 = b << 9;
    const int ebase = boff[b];
    const int ecnt = boff[b + 1] - ebase;

    sdeg[t] = 0; sdeg[t + 256] = 0;
    __syncthreads();
    for (int s = t; s < ecnt; s += 256)
        atomicAdd(&sdeg[ebuf[ebase + s] >> 17], 1);
    __syncthreads();

    int d0 = sdeg[2 * t], d1 = sdeg[2 * t + 1];
    pr[t] = d0 + d1;
    __syncthreads();
    for (int d = 1; d < 256; d <<= 1) {
        int a = (t >= d) ? pr[t - d] : 0;
        __syncthreads();
        pr[t] += a;
        __syncthreads();
    }
    int ex = pr[t] - d0 - d1;
    lofs[2 * t] = ex;
    lofs[2 * t + 1] = ex + d0;
    scnt[2 * t] = 0; scnt[2 * t + 1] = 0;
    int n0 = node0 + 2 * t, n1 = n0 + 1;
    if (n0 < NN) { off_g[n0] = ebase + ex;      deg_g[n0] = d0; }
    if (n1 < NN) { off_g[n1] = ebase + ex + d0; deg_g[n1] = d1; }
    __syncthreads();

    for (int s = t; s < ecnt; s += 256) {
        unsigned v = ebuf[ebase + s];
        int dl = v >> 17;
        int c = atomicAdd(&scnt[dl], 1);
        ssrc[ebase + lofs[dl] + c] = (int)(v & 0x1FFFFu);
    }
}

// ---------------- prep: transpose+convert weights to bf16 ----------------
__global__ __launch_bounds__(256) void k_prep(const float* __restrict__ W,
                                              const float* __restrict__ fcW,
                                              ushort* __restrict__ Wt,
                                              ushort* __restrict__ fcWt) {
    int t = blockIdx.x * 256 + threadIdx.x;
    for (int i = t; i < DHID * DIN; i += gridDim.x * 256) {   // Wt[n][k]
        int n = i >> 8, k = i & 255;
        Wt[i] = f2bf(W[k * DHID + n]);
    }
    for (int i = t; i < NCLS * DHID; i += gridDim.x * 256) {  // fcWt[n][k]
        int n = i >> 7, k = i & 127;
        fcWt[i] = f2bf(fcW[k * NCLS + n]);
    }
}

// ---------------- GEMM1: featb = bf16(X) @ bf16(W), MFMA, pipelined ----------------
__global__ __launch_bounds__(256, 2) void gemm1(const float* __restrict__ X,
                                                const ushort* __restrict__ Wt,
                                                ushort* __restrict__ featb) {
    __shared__ ushort Xs[2][128 * 64];   // 2 x 16 KB, [row][k] swizzled
    __shared__ ushort Wl[2][128 * 64];   // 2 x 16 KB, [n][k] swizzled
    const int t = threadIdx.x;
    const int row0 = blockIdx.x * 128;

    int srow[4], ske[4];
#pragma unroll
    for (int i = 0; i < 4; i++) {
        int o = i * 4096 + t * 16;
        int row = o >> 7;
        int bl = (o & 127) ^ ((row & 7) << 4);
        srow[i] = row;
        ske[i] = bl >> 1;
    }

    float4 xr[4][2];
    uint4  wr[4];

#pragma unroll
    for (int i = 0; i < 4; i++) {
        int grow = row0 + srow[i];
        if (grow < NN) {
            const float4* p = (const float4*)(X + (size_t)grow * DIN + ske[i]);
            xr[i][0] = p[0]; xr[i][1] = p[1];
        } else {
            xr[i][0] = make_float4(0.f, 0.f, 0.f, 0.f);
            xr[i][1] = make_float4(0.f, 0.f, 0.f, 0.f);
        }
        wr[i] = *(const uint4*)(Wt + (size_t)srow[i] * DIN + ske[i]);
    }
#pragma unroll
    for (int i = 0; i < 4; i++) {
        int o = i * 4096 + t * 16;
        ushort8v b;
        b[0] = f2bf(xr[i][0].x); b[1] = f2bf(xr[i][0].y);
        b[2] = f2bf(xr[i][0].z); b[3] = f2bf(xr[i][0].w);
        b[4] = f2bf(xr[i][1].x); b[5] = f2bf(xr[i][1].y);
        b[6] = f2bf(xr[i][1].z); b[7] = f2bf(xr[i][1].w);
        *(ushort8v*)((char*)&Xs[0][0] + o) = b;
        *(uint4*)((char*)&Wl[0][0] + o) = wr[i];
    }
    __syncthreads();

    const int w = t >> 6, lane = t & 63;
    const int rbase = w * 32;
    const int lcol = lane & 15;
    const int kgrp = (lane >> 4) * 16;

    f32x4 acc[2][8];
#pragma unroll
    for (int r = 0; r < 2; r++)
#pragma unroll
        for (int c = 0; c < 8; c++) acc[r][c] = (f32x4){0.f, 0.f, 0.f, 0.f};

    for (int c = 0; c < 4; c++) {
        const int buf = c & 1;
        if (c < 3) {
            int k0g = (c + 1) * 64;
#pragma unroll
            for (int i = 0; i < 4; i++) {
                int grow = row0 + srow[i];
                if (grow < NN) {
                    const float4* p = (const float4*)(X + (size_t)grow * DIN + k0g + ske[i]);
                    xr[i][0] = p[0]; xr[i][1] = p[1];
                } else {
                    xr[i][0] = make_float4(0.f, 0.f, 0.f, 0.f);
                    xr[i][1] = make_float4(0.f, 0.f, 0.f, 0.f);
                }
                wr[i] = *(const uint4*)(Wt + (size_t)srow[i] * DIN + k0g + ske[i]);
            }
        }
        const char* xb = (const char*)&Xs[buf][0];
        const char* wb = (const char*)&Wl[buf][0];
#pragma unroll
        for (int k0 = 0; k0 < 2; k0++) {
            int kb = k0 * 64 + kgrp;
            bf16x8 a[2], b[8];
#pragma unroll
            for (int r = 0; r < 2; r++) {
                int row = rbase + r * 16 + lcol;
                a[r] = *(const bf16x8*)(xb + row * 128 + (kb ^ ((row & 7) << 4)));
            }
#pragma unroll
            for (int cc = 0; cc < 8; cc++) {
                int n = cc * 16 + lcol;
                b[cc] = *(const bf16x8*)(wb + n * 128 + (kb ^ ((n & 7) << 4)));
            }
#pragma unroll
            for (int r = 0; r < 2; r++)
#pragma unroll
                for (int cc = 0; cc < 8; cc++)
                    acc[r][cc] = __builtin_amdgcn_mfma_f32_16x16x32_bf16(a[r], b[cc], acc[r][cc], 0, 0, 0);
        }
        if (c < 3) {
#pragma unroll
            for (int i = 0; i < 4; i++) {
                int o = i * 4096 + t * 16;
                ushort8v b;
                b[0] = f2bf(xr[i][0].x); b[1] = f2bf(xr[i][0].y);
                b[2] = f2bf(xr[i][0].z); b[3] = f2bf(xr[i][0].w);
                b[4] = f2bf(xr[i][1].x); b[5] = f2bf(xr[i][1].y);
                b[6] = f2bf(xr[i][1].z); b[7] = f2bf(xr[i][1].w);
                *(ushort8v*)((char*)&Xs[buf ^ 1][0] + o) = b;
                *(uint4*)((char*)&Wl[buf ^ 1][0] + o) = wr[i];
            }
        }
        __syncthreads();
    }

    ushort* Os = (ushort*)Xs;
#pragma unroll
    for (int r = 0; r < 2; r++)
#pragma unroll
        for (int cc = 0; cc < 8; cc++)
#pragma unroll
            for (int i = 0; i < 4; i++) {
                int rloc = rbase + r * 16 + (lane >> 4) * 4 + i;
                int col = cc * 16 + lcol;
                Os[rloc * 128 + col] = f2bf(acc[r][cc][i]);
            }
    __syncthreads();
#pragma unroll
    for (int i = 0; i < 8; i++) {
        int u = i * 256 + t;
        int row = u >> 4;
        int grow = row0 + row;
        if (grow < NN)
            *(uint4*)(featb + (size_t)grow * 128 + (u & 15) * 8) =
                *(uint4*)((char*)Os + u * 16);
    }
}

// ---------------- el/er from bf16 feat ----------------
__global__ __launch_bounds__(256) void eler_b(const ushort* __restrict__ featb,
                                              const float* __restrict__ attn_l,
                                              const float* __restrict__ attn_r,
                                              float* __restrict__ el,
                                              float* __restrict__ er) {
    int n = blockIdx.x * 4 + threadIdx.x / 64;
    int lane = threadIdx.x & 63;
    if (n >= NN) return;
    ushort2 f = ((const ushort2*)(featb + (size_t)n * DHID))[lane];
    float f0 = bf2f(f.x), f1 = bf2f(f.y);
    float2 al = ((const float2*)attn_l)[lane];
    float2 ar = ((const float2*)attn_r)[lane];
    float pl = f0 * al.x + f1 * al.y;
    float pr = f0 * ar.x + f1 * ar.y;
#pragma unroll
    for (int off = 32; off; off >>= 1) {
        pl += __shfl_down(pl, off);
        pr += __shfl_down(pr, off);
    }
    if (lane == 0) { el[n] = pl; er[n] = pr; }
}

// ---------------- fused softmax + aggregate ----------------
// one wave per dst node; 4 groups of 16 lanes, group owns an edge, lane owns
// 8 of 128 columns (16B load). Unroll x4 -> 4 independent 16B loads in flight.
__global__ __launch_bounds__(256) void aggregate(const int* __restrict__ off,
                                                 const int* __restrict__ deg,
                                                 const int* __restrict__ ssrc,
                                                 const float* __restrict__ el,
                                                 const float* __restrict__ er,
                                                 const ushort* __restrict__ featb,
                                                 ushort* __restrict__ hb) {
    int d = blockIdx.x * 4 + (threadIdx.x >> 6);
    int lane = threadIdx.x & 63;
    if (d >= NN) return;
    const int start = off[d];
    const int dg = deg[d];
    const float erd = er[d];

    // pass 1: segment max (edge-per-lane)
    float m = -INFINITY;
    for (int j = lane; j < dg; j += 64) {
        int s = ssrc[start + j];
        float x = el[s] + erd;
        float e = x > 0.f ? x : NEG_SLOPE * x;
        m = fmaxf(m, e);
    }
#pragma unroll
    for (int o = 32; o; o >>= 1) m = fmaxf(m, __shfl_xor(m, o));

    // pass 2: groups of 16 lanes, edge-per-group, x4 unroll
    const int g = lane >> 4, lc = lane & 15;
    const ushort* fb = featb + lc * 8;
    float acc[8];
#pragma unroll
    for (int q = 0; q < 8; q++) acc[q] = 0.f;
    float wpart = 0.f;

    for (int c = 0; c < dg; c += 16) {
        int jv[4], sv[4];
        float wv[4];
        ushort8v fv[4];
#pragma unroll
        for (int u = 0; u < 4; u++) {
            jv[u] = c + g + u * 4;
            sv[u] = (jv[u] < dg) ? ssrc[start + jv[u]] : 0;
        }
#pragma unroll
        for (int u = 0; u < 4; u++)
            fv[u] = *(const ushort8v*)(fb + (size_t)sv[u] * DHID);
#pragma unroll
        for (int u = 0; u < 4; u++) {
            float x = el[sv[u]] + erd;
            float e = x > 0.f ? x : NEG_SLOPE * x;
            float we = expf(e - m);
            wv[u] = (jv[u] < dg) ? we : 0.f;
            wpart += wv[u];
        }
#pragma unroll
        for (int u = 0; u < 4; u++)
#pragma unroll
            for (int q = 0; q < 8; q++)
                acc[q] += wv[u] * bf2f(fv[u][q]);
    }

    // cross-group reduction (lanes lc, lc+16, lc+32, lc+48 hold same cols)
#pragma unroll
    for (int q = 0; q < 8; q++) {
        acc[q] += __shfl_xor(acc[q], 16);
        acc[q] += __shfl_xor(acc[q], 32);
    }
    float dsum = (lc == 0) ? wpart : 0.f;
#pragma unroll
    for (int o = 32; o; o >>= 1) dsum += __shfl_xor(dsum, o);

    if (g == 0) {
        float inv = (dg > 0) ? 1.0f / dsum : 0.f;
        ushort8v o8;
#pragma unroll
        for (int q = 0; q < 8; q++) o8[q] = f2bf(acc[q] * inv);
        *(ushort8v*)(hb + (size_t)d * DHID + lc * 8) = o8;
    }
}

// ---------------- GEMM2: out = bf16(h) @ bf16(fcW) + fcb, MFMA ----------------
__global__ __launch_bounds__(256) void gemm2(const ushort* __restrict__ hb,
                                             const ushort* __restrict__ fcWt,
                                             const float* __restrict__ fcb,
                                             float* __restrict__ out) {
    __shared__ ushort Hs[128 * 128];
    __shared__ ushort Fs[64 * 128];
    __shared__ float  Os[128 * 64];
    const int t = threadIdx.x;
    const int row0 = blockIdx.x * 128;

    {
#pragma unroll
        for (int i = 0; i < 8; i++) {
            int u = i * 256 + t;
            int row = u >> 4;
            int grow = row0 + row;
            uint4 v = make_uint4(0, 0, 0, 0);
            if (grow < NN) v = *(const uint4*)(hb + (size_t)grow * 128 + (u & 15) * 8);
            int byte_off = row * 256 + (((u & 15) * 16) ^ ((row & 7) << 4));
            *(uint4*)((char*)Hs + byte_off) = v;
        }
#pragma unroll
        for (int i = 0; i < 4; i++) {
            int u = i * 256 + t;
            int n = u >> 4;
            int byte_off = n * 256 + (((u & 15) * 16) ^ ((n & 7) << 4));
            *(uint4*)((char*)Fs + byte_off) = ((const uint4*)fcWt)[u];
        }
    }
    __syncthreads();

    const int w = t >> 6, lane = t & 63;
    const int rbase = w * 32;
    const int lcol = lane & 15;
    const int kgrp = (lane >> 4) * 16;

    f32x4 acc[2][4];
#pragma unroll
    for (int r = 0; r < 2; r++)
#pragma unroll
        for (int c = 0; c < 4; c++) acc[r][c] = (f32x4){0.f, 0.f, 0.f, 0.f};

#pragma unroll
    for (int k0 = 0; k0 < 4; k0++) {
        int kbyte = k0 * 64 + kgrp;
        bf16x8 a[2], b[4];
#pragma unroll
        for (int r = 0; r < 2; r++) {
            int row = rbase + r * 16 + lcol;
            a[r] = *(bf16x8*)((char*)Hs + row * 256 + (kbyte ^ ((row & 7) << 4)));
        }
#pragma unroll
        for (int c = 0; c < 4; c++) {
            int n = c * 16 + lcol;
            b[c] = *(bf16x8*)((char*)Fs + n * 256 + (kbyte ^ ((n & 7) << 4)));
        }
#pragma unroll
        for (int r = 0; r < 2; r++)
#pragma unroll
            for (int c = 0; c < 4; c++)
                acc[r][c] = __builtin_amdgcn_mfma_f32_16x16x32_bf16(a[r], b[c], acc[r][c], 0, 0, 0);
    }

#pragma unroll
    for (int r = 0; r < 2; r++)
#pragma unroll
        for (int c = 0; c < 4; c++) {
            int col = c * 16 + lcol;
            float bias = fcb[col];
#pragma unroll
            for (int i = 0; i < 4; i++) {
                int rloc = rbase + r * 16 + (lane >> 4) * 4 + i;
                Os[rloc * 64 + col] = acc[r][c][i] + bias;
            }
        }
    __syncthreads();
#pragma unroll
    for (int i = 0; i < 8; i++) {
        int u = i * 256 + t;
        int row = u >> 4;
        int grow = row0 + row;
        if (grow < NN)
            *(float4*)(out + (size_t)grow * 64 + (u & 15) * 4) = ((float4*)Os)[u];
    }
}

// ---------------- launch ----------------
extern "C" void kernel_launch(void* const* d_in, const int* in_sizes, int n_in,
                              void* d_out, int out_size, void* d_ws, size_t ws_size,
                              hipStream_t stream) {
    const float* X      = (const float*)d_in[0];
    const float* W      = (const float*)d_in[1];
    const float* attn_l = (const float*)d_in[2];
    const float* attn_r = (const float*)d_in[3];
    const float* fcW    = (const float*)d_in[4];
    const float* fcb    = (const float*)d_in[5];
    const int*   src    = (const int*)d_in[6];
    const int*   dst    = (const int*)d_in[7];
    float* out = (float*)d_out;

    char* ws = (char*)d_ws;
    ushort* featb = (ushort*)ws;            ws += (size_t)NN * DHID * 2;
    ushort* hb    = (ushort*)ws;            ws += (size_t)NN * DHID * 2;
    ushort* Wt    = (ushort*)ws;            ws += (size_t)DHID * DIN * 2;
    ushort* fcWt  = (ushort*)ws;            ws += (size_t)NCLS * DHID * 2;
    float* el     = (float*)ws;             ws += (size_t)NN * 4;
    float* er     = (float*)ws;             ws += (size_t)NN * 4;
    int*   deg    = (int*)ws;               ws += (size_t)NN * 4;
    int*   off    = (int*)ws;               ws += (size_t)NN * 4;
    int*   ssrc   = (int*)ws;               ws += (size_t)NE * 4;
    unsigned* ebuf = (unsigned*)ws;         ws += (size_t)NE * 4;
    int*   ghist  = (int*)ws;               ws += (size_t)256 * 4;
    int*   boff   = (int*)ws;               ws += (size_t)256 * 4;
    int*   gcur   = (int*)ws;               ws += (size_t)256 * 4;

    hipMemsetAsync(ghist, 0, NBUCK * sizeof(int), stream);

    // CSR build (bucketed counting sort)
    k_ghist<<<NCHB, 256, 0, stream>>>(dst, ghist);
    k_prep<<<64, 256, 0, stream>>>(W, fcW, Wt, fcWt);
    k_gscan<<<1, 256, 0, stream>>>(ghist, boff, gcur);
    k_bin<<<NCHB, 256, 0, stream>>>(src, dst, gcur, ebuf);
    k_csr<<<NBUCK, 256, 0, stream>>>(ebuf, boff, off, deg, ssrc);

    // dense pipeline (bf16 MFMA)
    gemm1<<<(NN + 127) / 128, 256, 0, stream>>>(X, Wt, featb);
    eler_b<<<(NN + 3) / 4, 256, 0, stream>>>(featb, attn_l, attn_r, el, er);
    aggregate<<<(NN + 3) / 4, 256, 0, stream>>>(off, deg, ssrc, el, er, featb, hb);
    gemm2<<<(NN + 127) / 128, 256, 0, stream>>>(hb, fcWt, fcb, out);
}

// Round 7
// 192.536 us; speedup vs baseline: 1.0678x; 1.0678x over previous
//
#include <hip/hip_runtime.h>
#include <math.h>

#define NN 100000
#define NE 1600000
#define DIN 256
#define DHID 128
#define NCLS 64
#define NEG_SLOPE 0.2f

#define NBUCK 196          // ceil(NN / 512), bucket = dst >> 9
#define CHUNK 4096
#define NCHB ((NE + CHUNK - 1) / CHUNK)   // 391

#define NGRP 16384         // edge-balanced 16-lane groups for aggregate

typedef __bf16 bf16_t;
typedef bf16_t bf16x8 __attribute__((ext_vector_type(8)));
typedef float f32x4 __attribute__((ext_vector_type(4)));
typedef ushort ushort8v __attribute__((ext_vector_type(8)));

__device__ __forceinline__ ushort f2bf(float f) {
    union { float f; unsigned u; } c; c.f = f;
    unsigned u = c.u;
    unsigned r = (u + 0x7FFFu + ((u >> 16) & 1u)) >> 16;
    return (ushort)r;
}
__device__ __forceinline__ float bf2f(ushort b) {
    return __uint_as_float(((unsigned)b) << 16);
}

// ================= CSR build: bucketed counting sort =================
__global__ __launch_bounds__(256) void k_ghist(const int* __restrict__ dst,
                                               int* __restrict__ ghist) {
    __shared__ int h[NBUCK];
    int t = threadIdx.x;
    for (int i = t; i < NBUCK; i += 256) h[i] = 0;
    __syncthreads();
    int base = blockIdx.x * CHUNK;
    int end = base + CHUNK; if (end > NE) end = NE;
    for (int idx = base + t; idx < end; idx += 256)
        atomicAdd(&h[dst[idx] >> 9], 1);
    __syncthreads();
    for (int i = t; i < NBUCK; i += 256)
        if (h[i]) atomicAdd(&ghist[i], h[i]);
}

__global__ __launch_bounds__(256) void k_gscan(const int* __restrict__ ghist,
                                               int* __restrict__ boff,
                                               int* __restrict__ gcur) {
    __shared__ int sh[256];
    int t = threadIdx.x;
    int v = (t < NBUCK) ? ghist[t] : 0;
    sh[t] = v;
    __syncthreads();
    for (int d = 1; d < 256; d <<= 1) {
        int a = (t >= d) ? sh[t - d] : 0;
        __syncthreads();
        sh[t] += a;
        __syncthreads();
    }
    if (t < NBUCK) {
        int ex = sh[t] - v;
        boff[t] = ex;
        gcur[t] = ex;
        if (t == NBUCK - 1) boff[NBUCK] = sh[t];
    }
}

__global__ __launch_bounds__(256) void k_bin(const int* __restrict__ src,
                                             const int* __restrict__ dst,
                                             int* __restrict__ gcur,
                                             unsigned* __restrict__ ebuf) {
    __shared__ int hist[NBUCK];
    __shared__ int scn[256];
    __shared__ int loff[NBUCK];
    __shared__ int cur[NBUCK];
    __shared__ int gb[NBUCK];
    __shared__ unsigned ord[CHUNK];
    __shared__ ushort obk[CHUNK];
    const int t = threadIdx.x;
    const int base = blockIdx.x * CHUNK;
    int cnt = NE - base; if (cnt > CHUNK) cnt = CHUNK;

    for (int i = t; i < NBUCK; i += 256) hist[i] = 0;
    __syncthreads();

    unsigned vals[16];
    int bks[16];
#pragma unroll
    for (int i = 0; i < 16; i++) {
        int idx = base + i * 256 + t;
        if (idx < NE) {
            int d = dst[idx], s = src[idx];
            int bb = d >> 9;
            bks[i] = bb;
            vals[i] = ((unsigned)(d & 511) << 17) | (unsigned)s;
            atomicAdd(&hist[bb], 1);
        } else bks[i] = -1;
    }
    __syncthreads();

    int hv = (t < NBUCK) ? hist[t] : 0;
    scn[t] = hv;
    __syncthreads();
    for (int d = 1; d < 256; d <<= 1) {
        int a = (t >= d) ? scn[t - d] : 0;
        __syncthreads();
        scn[t] += a;
        __syncthreads();
    }
    if (t < NBUCK) { loff[t] = scn[t] - hv; cur[t] = scn[t] - hv; }
    __syncthreads();

#pragma unroll
    for (int i = 0; i < 16; i++) {
        if (bks[i] >= 0) {
            int slot = atomicAdd(&cur[bks[i]], 1);
            ord[slot] = vals[i];
            obk[slot] = (ushort)bks[i];
        }
    }
    if (t < NBUCK && hv > 0) gb[t] = atomicAdd(&gcur[t], hv);
    __syncthreads();

    for (int s = t; s < cnt; s += 256) {
        int bb = obk[s];
        ebuf[gb[bb] + (s - loff[bb])] = ord[s];
    }
}

__global__ __launch_bounds__(256) void k_csr(const unsigned* __restrict__ ebuf,
                                             const int* __restrict__ boff,
                                             int* __restrict__ off_g,
                                             int* __restrict__ deg_g,
                                             int* __restrict__ ssrc) {
    __shared__ int sdeg[512];
    __shared__ int pr[256];
    __shared__ int lofs[512];
    __shared__ int scnt[512];
    const int b = blockIdx.x, t = threadIdx.x;
    const int node0 = b << 9;
    const int ebase = boff[b];
    const int ecnt = boff[b + 1] - ebase;

    sdeg[t] = 0; sdeg[t + 256] = 0;
    __syncthreads();
    for (int s = t; s < ecnt; s += 256)
        atomicAdd(&sdeg[ebuf[ebase + s] >> 17], 1);
    __syncthreads();

    int d0 = sdeg[2 * t], d1 = sdeg[2 * t + 1];
    pr[t] = d0 + d1;
    __syncthreads();
    for (int d = 1; d < 256; d <<= 1) {
        int a = (t >= d) ? pr[t - d] : 0;
        __syncthreads();
        pr[t] += a;
        __syncthreads();
    }
    int ex = pr[t] - d0 - d1;
    lofs[2 * t] = ex;
    lofs[2 * t + 1] = ex + d0;
    scnt[2 * t] = 0; scnt[2 * t + 1] = 0;
    int n0 = node0 + 2 * t, n1 = n0 + 1;
    if (n0 < NN) { off_g[n0] = ebase + ex;      deg_g[n0] = d0; }
    if (n1 < NN) { off_g[n1] = ebase + ex + d0; deg_g[n1] = d1; }
    __syncthreads();

    for (int s = t; s < ecnt; s += 256) {
        unsigned v = ebuf[ebase + s];
        int dl = v >> 17;
        int c = atomicAdd(&scnt[dl], 1);
        ssrc[ebase + lofs[dl] + c] = (int)(v & 0x1FFFFu);
    }
}

// ---------------- edge-balanced group partition (binary search) ----------------
__global__ __launch_bounds__(256) void k_split(const int* __restrict__ off,
                                               int* __restrict__ nsplit) {
    int g = blockIdx.x * 256 + threadIdx.x;
    if (g > NGRP) return;
    if (g == NGRP) { nsplit[NGRP] = NN; return; }
    long target = (long)g * NE / NGRP;
    int lo = 0, hi = NN;          // smallest n with off[n] >= target
    while (lo < hi) {
        int mid = (lo + hi) >> 1;
        if (off[mid] < (int)target) lo = mid + 1; else hi = mid;
    }
    nsplit[g] = lo;
}

// ---------------- prep: transpose+convert weights to bf16 ----------------
__global__ __launch_bounds__(256) void k_prep(const float* __restrict__ W,
                                              const float* __restrict__ fcW,
                                              ushort* __restrict__ Wt,
                                              ushort* __restrict__ fcWt) {
    int t = blockIdx.x * 256 + threadIdx.x;
    for (int i = t; i < DHID * DIN; i += gridDim.x * 256) {   // Wt[n][k]
        int n = i >> 8, k = i & 255;
        Wt[i] = f2bf(W[k * DHID + n]);
    }
    for (int i = t; i < NCLS * DHID; i += gridDim.x * 256) {  // fcWt[n][k]
        int n = i >> 7, k = i & 127;
        fcWt[i] = f2bf(fcW[k * NCLS + n]);
    }
}

// ---------------- GEMM1: featb = bf16(X) @ bf16(W), MFMA, pipelined ----------------
__global__ __launch_bounds__(256, 2) void gemm1(const float* __restrict__ X,
                                                const ushort* __restrict__ Wt,
                                                ushort* __restrict__ featb) {
    __shared__ ushort Xs[2][128 * 64];   // 2 x 16 KB, [row][k] swizzled
    __shared__ ushort Wl[2][128 * 64];   // 2 x 16 KB, [n][k] swizzled
    const int t = threadIdx.x;
    const int row0 = blockIdx.x * 128;

    int srow[4], ske[4];
#pragma unroll
    for (int i = 0; i < 4; i++) {
        int o = i * 4096 + t * 16;
        int row = o >> 7;
        int bl = (o & 127) ^ ((row & 7) << 4);
        srow[i] = row;
        ske[i] = bl >> 1;
    }

    float4 xr[4][2];
    uint4  wr[4];

#pragma unroll
    for (int i = 0; i < 4; i++) {
        int grow = row0 + srow[i];
        if (grow < NN) {
            const float4* p = (const float4*)(X + (size_t)grow * DIN + ske[i]);
            xr[i][0] = p[0]; xr[i][1] = p[1];
        } else {
            xr[i][0] = make_float4(0.f, 0.f, 0.f, 0.f);
            xr[i][1] = make_float4(0.f, 0.f, 0.f, 0.f);
        }
        wr[i] = *(const uint4*)(Wt + (size_t)srow[i] * DIN + ske[i]);
    }
#pragma unroll
    for (int i = 0; i < 4; i++) {
        int o = i * 4096 + t * 16;
        ushort8v b;
        b[0] = f2bf(xr[i][0].x); b[1] = f2bf(xr[i][0].y);
        b[2] = f2bf(xr[i][0].z); b[3] = f2bf(xr[i][0].w);
        b[4] = f2bf(xr[i][1].x); b[5] = f2bf(xr[i][1].y);
        b[6] = f2bf(xr[i][1].z); b[7] = f2bf(xr[i][1].w);
        *(ushort8v*)((char*)&Xs[0][0] + o) = b;
        *(uint4*)((char*)&Wl[0][0] + o) = wr[i];
    }
    __syncthreads();

    const int w = t >> 6, lane = t & 63;
    const int rbase = w * 32;
    const int lcol = lane & 15;
    const int kgrp = (lane >> 4) * 16;

    f32x4 acc[2][8];
#pragma unroll
    for (int r = 0; r < 2; r++)
#pragma unroll
        for (int c = 0; c < 8; c++) acc[r][c] = (f32x4){0.f, 0.f, 0.f, 0.f};

    for (int c = 0; c < 4; c++) {
        const int buf = c & 1;
        if (c < 3) {
            int k0g = (c + 1) * 64;
#pragma unroll
            for (int i = 0; i < 4; i++) {
                int grow = row0 + srow[i];
                if (grow < NN) {
                    const float4* p = (const float4*)(X + (size_t)grow * DIN + k0g + ske[i]);
                    xr[i][0] = p[0]; xr[i][1] = p[1];
                } else {
                    xr[i][0] = make_float4(0.f, 0.f, 0.f, 0.f);
                    xr[i][1] = make_float4(0.f, 0.f, 0.f, 0.f);
                }
                wr[i] = *(const uint4*)(Wt + (size_t)srow[i] * DIN + k0g + ske[i]);
            }
        }
        const char* xb = (const char*)&Xs[buf][0];
        const char* wb = (const char*)&Wl[buf][0];
#pragma unroll
        for (int k0 = 0; k0 < 2; k0++) {
            int kb = k0 * 64 + kgrp;
            bf16x8 a[2], b[8];
#pragma unroll
            for (int r = 0; r < 2; r++) {
                int row = rbase + r * 16 + lcol;
                a[r] = *(const bf16x8*)(xb + row * 128 + (kb ^ ((row & 7) << 4)));
            }
#pragma unroll
            for (int cc = 0; cc < 8; cc++) {
                int n = cc * 16 + lcol;
                b[cc] = *(const bf16x8*)(wb + n * 128 + (kb ^ ((n & 7) << 4)));
            }
#pragma unroll
            for (int r = 0; r < 2; r++)
#pragma unroll
                for (int cc = 0; cc < 8; cc++)
                    acc[r][cc] = __builtin_amdgcn_mfma_f32_16x16x32_bf16(a[r], b[cc], acc[r][cc], 0, 0, 0);
        }
        if (c < 3) {
#pragma unroll
            for (int i = 0; i < 4; i++) {
                int o = i * 4096 + t * 16;
                ushort8v b;
                b[0] = f2bf(xr[i][0].x); b[1] = f2bf(xr[i][0].y);
                b[2] = f2bf(xr[i][0].z); b[3] = f2bf(xr[i][0].w);
                b[4] = f2bf(xr[i][1].x); b[5] = f2bf(xr[i][1].y);
                b[6] = f2bf(xr[i][1].z); b[7] = f2bf(xr[i][1].w);
                *(ushort8v*)((char*)&Xs[buf ^ 1][0] + o) = b;
                *(uint4*)((char*)&Wl[buf ^ 1][0] + o) = wr[i];
            }
        }
        __syncthreads();
    }

    ushort* Os = (ushort*)Xs;
#pragma unroll
    for (int r = 0; r < 2; r++)
#pragma unroll
        for (int cc = 0; cc < 8; cc++)
#pragma unroll
            for (int i = 0; i < 4; i++) {
                int rloc = rbase + r * 16 + (lane >> 4) * 4 + i;
                int col = cc * 16 + lcol;
                Os[rloc * 128 + col] = f2bf(acc[r][cc][i]);
            }
    __syncthreads();
#pragma unroll
    for (int i = 0; i < 8; i++) {
        int u = i * 256 + t;
        int row = u >> 4;
        int grow = row0 + row;
        if (grow < NN)
            *(uint4*)(featb + (size_t)grow * 128 + (u & 15) * 8) =
                *(uint4*)((char*)Os + u * 16);
    }
}

// ---------------- el/er from bf16 feat ----------------
__global__ __launch_bounds__(256) void eler_b(const ushort* __restrict__ featb,
                                              const float* __restrict__ attn_l,
                                              const float* __restrict__ attn_r,
                                              float* __restrict__ el,
                                              float* __restrict__ er) {
    int n = blockIdx.x * 4 + threadIdx.x / 64;
    int lane = threadIdx.x & 63;
    if (n >= NN) return;
    ushort2 f = ((const ushort2*)(featb + (size_t)n * DHID))[lane];
    float f0 = bf2f(f.x), f1 = bf2f(f.y);
    float2 al = ((const float2*)attn_l)[lane];
    float2 ar = ((const float2*)attn_r)[lane];
    float pl = f0 * al.x + f1 * al.y;
    float pr = f0 * ar.x + f1 * ar.y;
#pragma unroll
    for (int off = 32; off; off >>= 1) {
        pl += __shfl_down(pl, off);
        pr += __shfl_down(pr, off);
    }
    if (lane == 0) { el[n] = pl; er[n] = pr; }
}

// ---------------- fused softmax + aggregate, v4 ----------------
// 16-lane group per node (lane owns 8 cols); groups get edge-balanced node
// ranges via nsplit. No max pass (exp range safe), no cross-lane reductions
// (wsum is uniform within group; acc is lane-private).
__global__ __launch_bounds__(256) void aggregate(const int* __restrict__ off,
                                                 const int* __restrict__ deg,
                                                 const int* __restrict__ ssrc,
                                                 const float* __restrict__ el,
                                                 const float* __restrict__ er,
                                                 const ushort* __restrict__ featb,
                                                 ushort* __restrict__ hb,
                                                 const int* __restrict__ nsplit) {
    const int gid = blockIdx.x * 16 + (threadIdx.x >> 4);
    const int lc = threadIdx.x & 15;
    int n = nsplit[gid];
    const int nend = nsplit[gid + 1];
    const ushort* fb = featb + lc * 8;

    for (; n < nend; ++n) {
        const int e0 = off[n];
        const int dg = deg[n];
        const float erd = er[n];
        float acc[8];
#pragma unroll
        for (int q = 0; q < 8; q++) acc[q] = 0.f;
        float wsum = 0.f;

        int j = 0;
        for (; j + 4 <= dg; j += 4) {
            int s0 = ssrc[e0 + j + 0];
            int s1 = ssrc[e0 + j + 1];
            int s2 = ssrc[e0 + j + 2];
            int s3 = ssrc[e0 + j + 3];
            ushort8v f0 = *(const ushort8v*)(fb + (size_t)s0 * DHID);
            ushort8v f1 = *(const ushort8v*)(fb + (size_t)s1 * DHID);
            ushort8v f2 = *(const ushort8v*)(fb + (size_t)s2 * DHID);
            ushort8v f3 = *(const ushort8v*)(fb + (size_t)s3 * DHID);
            float x0 = el[s0] + erd, x1 = el[s1] + erd;
            float x2 = el[s2] + erd, x3 = el[s3] + erd;
            x0 = x0 > 0.f ? x0 : NEG_SLOPE * x0;
            x1 = x1 > 0.f ? x1 : NEG_SLOPE * x1;
            x2 = x2 > 0.f ? x2 : NEG_SLOPE * x2;
            x3 = x3 > 0.f ? x3 : NEG_SLOPE * x3;
            float w0 = __expf(x0), w1 = __expf(x1);
            float w2 = __expf(x2), w3 = __expf(x3);
            wsum += (w0 + w1) + (w2 + w3);
#pragma unroll
            for (int q = 0; q < 8; q++)
                acc[q] += (w0 * bf2f(f0[q]) + w1 * bf2f(f1[q])) +
                          (w2 * bf2f(f2[q]) + w3 * bf2f(f3[q]));
        }
        for (; j < dg; ++j) {
            int s0 = ssrc[e0 + j];
            ushort8v f0 = *(const ushort8v*)(fb + (size_t)s0 * DHID);
            float x0 = el[s0] + erd;
            x0 = x0 > 0.f ? x0 : NEG_SLOPE * x0;
            float w0 = __expf(x0);
            wsum += w0;
#pragma unroll
            for (int q = 0; q < 8; q++) acc[q] += w0 * bf2f(f0[q]);
        }

        float inv = (dg > 0) ? 1.0f / wsum : 0.f;
        ushort8v o8;
#pragma unroll
        for (int q = 0; q < 8; q++) o8[q] = f2bf(acc[q] * inv);
        *(ushort8v*)(hb + (size_t)n * DHID + lc * 8) = o8;
    }
}

// ---------------- GEMM2: out = bf16(h) @ bf16(fcW) + fcb, MFMA ----------------
__global__ __launch_bounds__(256) void gemm2(const ushort* __restrict__ hb,
                                             const ushort* __restrict__ fcWt,
                                             const float* __restrict__ fcb,
                                             float* __restrict__ out) {
    __shared__ ushort Hs[128 * 128];
    __shared__ ushort Fs[64 * 128];
    __shared__ float  Os[128 * 64];
    const int t = threadIdx.x;
    const int row0 = blockIdx.x * 128;

    {
#pragma unroll
        for (int i = 0; i < 8; i++) {
            int u = i * 256 + t;
            int row = u >> 4;
            int grow = row0 + row;
            uint4 v = make_uint4(0, 0, 0, 0);
            if (grow < NN) v = *(const uint4*)(hb + (size_t)grow * 128 + (u & 15) * 8);
            int byte_off = row * 256 + (((u & 15) * 16) ^ ((row & 7) << 4));
            *(uint4*)((char*)Hs + byte_off) = v;
        }
#pragma unroll
        for (int i = 0; i < 4; i++) {
            int u = i * 256 + t;
            int n = u >> 4;
            int byte_off = n * 256 + (((u & 15) * 16) ^ ((n & 7) << 4));
            *(uint4*)((char*)Fs + byte_off) = ((const uint4*)fcWt)[u];
        }
    }
    __syncthreads();

    const int w = t >> 6, lane = t & 63;
    const int rbase = w * 32;
    const int lcol = lane & 15;
    const int kgrp = (lane >> 4) * 16;

    f32x4 acc[2][4];
#pragma unroll
    for (int r = 0; r < 2; r++)
#pragma unroll
        for (int c = 0; c < 4; c++) acc[r][c] = (f32x4){0.f, 0.f, 0.f, 0.f};

#pragma unroll
    for (int k0 = 0; k0 < 4; k0++) {
        int kbyte = k0 * 64 + kgrp;
        bf16x8 a[2], b[4];
#pragma unroll
        for (int r = 0; r < 2; r++) {
            int row = rbase + r * 16 + lcol;
            a[r] = *(bf16x8*)((char*)Hs + row * 256 + (kbyte ^ ((row & 7) << 4)));
        }
#pragma unroll
        for (int c = 0; c < 4; c++) {
            int n = c * 16 + lcol;
            b[c] = *(bf16x8*)((char*)Fs + n * 256 + (kbyte ^ ((n & 7) << 4)));
        }
#pragma unroll
        for (int r = 0; r < 2; r++)
#pragma unroll
            for (int c = 0; c < 4; c++)
                acc[r][c] = __builtin_amdgcn_mfma_f32_16x16x32_bf16(a[r], b[c], acc[r][c], 0, 0, 0);
    }

#pragma unroll
    for (int r = 0; r < 2; r++)
#pragma unroll
        for (int c = 0; c < 4; c++) {
            int col = c * 16 + lcol;
            float bias = fcb[col];
#pragma unroll
            for (int i = 0; i < 4; i++) {
                int rloc = rbase + r * 16 + (lane >> 4) * 4 + i;
                Os[rloc * 64 + col] = acc[r][c][i] + bias;
            }
        }
    __syncthreads();
#pragma unroll
    for (int i = 0; i < 8; i++) {
        int u = i * 256 + t;
        int row = u >> 4;
        int grow = row0 + row;
        if (grow < NN)
            *(float4*)(out + (size_t)grow * 64 + (u & 15) * 4) = ((float4*)Os)[u];
    }
}

// ---------------- launch ----------------
extern "C" void kernel_launch(void* const* d_in, const int* in_sizes, int n_in,
                              void* d_out, int out_size, void* d_ws, size_t ws_size,
                              hipStream_t stream) {
    const float* X      = (const float*)d_in[0];
    const float* W      = (const float*)d_in[1];
    const float* attn_l = (const float*)d_in[2];
    const float* attn_r = (const float*)d_in[3];
    const float* fcW    = (const float*)d_in[4];
    const float* fcb    = (const float*)d_in[5];
    const int*   src    = (const int*)d_in[6];
    const int*   dst    = (const int*)d_in[7];
    float* out = (float*)d_out;

    char* ws = (char*)d_ws;
    ushort* featb = (ushort*)ws;            ws += (size_t)NN * DHID * 2;
    ushort* hb    = (ushort*)ws;            ws += (size_t)NN * DHID * 2;
    ushort* Wt    = (ushort*)ws;            ws += (size_t)DHID * DIN * 2;
    ushort* fcWt  = (ushort*)ws;            ws += (size_t)NCLS * DHID * 2;
    float* el     = (float*)ws;             ws += (size_t)NN * 4;
    float* er     = (float*)ws;             ws += (size_t)NN * 4;
    int*   deg    = (int*)ws;               ws += (size_t)NN * 4;
    int*   off    = (int*)ws;               ws += (size_t)NN * 4;
    int*   ssrc   = (int*)ws;               ws += (size_t)NE * 4;
    unsigned* ebuf = (unsigned*)ws;         ws += (size_t)NE * 4;
    int*   ghist  = (int*)ws;               ws += (size_t)256 * 4;
    int*   boff   = (int*)ws;               ws += (size_t)256 * 4;
    int*   gcur   = (int*)ws;               ws += (size_t)256 * 4;
    int*   nsplit = (int*)ws;               ws += (size_t)(NGRP + 1) * 4;

    hipMemsetAsync(ghist, 0, NBUCK * sizeof(int), stream);

    // CSR build (bucketed counting sort)
    k_ghist<<<NCHB, 256, 0, stream>>>(dst, ghist);
    k_prep<<<64, 256, 0, stream>>>(W, fcW, Wt, fcWt);
    k_gscan<<<1, 256, 0, stream>>>(ghist, boff, gcur);
    k_bin<<<NCHB, 256, 0, stream>>>(src, dst, gcur, ebuf);
    k_csr<<<NBUCK, 256, 0, stream>>>(ebuf, boff, off, deg, ssrc);
    k_split<<<(NGRP + 256) / 256, 256, 0, stream>>>(off, nsplit);

    // dense pipeline (bf16 MFMA)
    gemm1<<<(NN + 127) / 128, 256, 0, stream>>>(X, Wt, featb);
    eler_b<<<(NN + 3) / 4, 256, 0, stream>>>(featb, attn_l, attn_r, el, er);
    aggregate<<<NGRP / 16, 256, 0, stream>>>(off, deg, ssrc, el, er, featb, hb, nsplit);
    gemm2<<<(NN + 127) / 128, 256, 0, stream>>>(hb, fcWt, fcb, out);
}

// Round 8
// 186.077 us; speedup vs baseline: 1.1048x; 1.0347x over previous
//
#include <hip/hip_runtime.h>
#include <math.h>

#define NN 100000
#define NE 1600000
#define DIN 256
#define DHID 128
#define NCLS 64
#define NEG_SLOPE 0.2f

#define NBUCK 196          // ceil(NN / 512), bucket = dst >> 9
#define CHUNK 4096
#define NCHB ((NE + CHUNK - 1) / CHUNK)   // 391

#define NGRP 32768         // edge-balanced 16-lane groups for aggregate

typedef __bf16 bf16_t;
typedef bf16_t bf16x8 __attribute__((ext_vector_type(8)));
typedef float f32x4 __attribute__((ext_vector_type(4)));
typedef ushort ushort8v __attribute__((ext_vector_type(8)));

__device__ __forceinline__ ushort f2bf(float f) {
    union { float f; unsigned u; } c; c.f = f;
    unsigned u = c.u;
    unsigned r = (u + 0x7FFFu + ((u >> 16) & 1u)) >> 16;
    return (ushort)r;
}
__device__ __forceinline__ float bf2f(ushort b) {
    return __uint_as_float(((unsigned)b) << 16);
}

// ================= CSR build: bucketed counting sort =================
__global__ __launch_bounds__(256) void k_ghist(const int* __restrict__ dst,
                                               int* __restrict__ ghist) {
    __shared__ int h[NBUCK];
    int t = threadIdx.x;
    for (int i = t; i < NBUCK; i += 256) h[i] = 0;
    __syncthreads();
    int base = blockIdx.x * CHUNK;
    int end = base + CHUNK; if (end > NE) end = NE;
    for (int idx = base + t; idx < end; idx += 256)
        atomicAdd(&h[dst[idx] >> 9], 1);
    __syncthreads();
    for (int i = t; i < NBUCK; i += 256)
        if (h[i]) atomicAdd(&ghist[i], h[i]);
}

__global__ __launch_bounds__(256) void k_gscan(const int* __restrict__ ghist,
                                               int* __restrict__ boff,
                                               int* __restrict__ gcur) {
    __shared__ int sh[256];
    int t = threadIdx.x;
    int v = (t < NBUCK) ? ghist[t] : 0;
    sh[t] = v;
    __syncthreads();
    for (int d = 1; d < 256; d <<= 1) {
        int a = (t >= d) ? sh[t - d] : 0;
        __syncthreads();
        sh[t] += a;
        __syncthreads();
    }
    if (t < NBUCK) {
        int ex = sh[t] - v;
        boff[t] = ex;
        gcur[t] = ex;
        if (t == NBUCK - 1) boff[NBUCK] = sh[t];
    }
}

__global__ __launch_bounds__(256) void k_bin(const int* __restrict__ src,
                                             const int* __restrict__ dst,
                                             int* __restrict__ gcur,
                                             unsigned* __restrict__ ebuf) {
    __shared__ int hist[NBUCK];
    __shared__ int scn[256];
    __shared__ int loff[NBUCK];
    __shared__ int cur[NBUCK];
    __shared__ int gb[NBUCK];
    __shared__ unsigned ord[CHUNK];
    __shared__ ushort obk[CHUNK];
    const int t = threadIdx.x;
    const int base = blockIdx.x * CHUNK;
    int cnt = NE - base; if (cnt > CHUNK) cnt = CHUNK;

    for (int i = t; i < NBUCK; i += 256) hist[i] = 0;
    __syncthreads();

    unsigned vals[16];
    int bks[16];
#pragma unroll
    for (int i = 0; i < 16; i++) {
        int idx = base + i * 256 + t;
        if (idx < NE) {
            int d = dst[idx], s = src[idx];
            int bb = d >> 9;
            bks[i] = bb;
            vals[i] = ((unsigned)(d & 511) << 17) | (unsigned)s;
            atomicAdd(&hist[bb], 1);
        } else bks[i] = -1;
    }
    __syncthreads();

    int hv = (t < NBUCK) ? hist[t] : 0;
    scn[t] = hv;
    __syncthreads();
    for (int d = 1; d < 256; d <<= 1) {
        int a = (t >= d) ? scn[t - d] : 0;
        __syncthreads();
        scn[t] += a;
        __syncthreads();
    }
    if (t < NBUCK) { loff[t] = scn[t] - hv; cur[t] = scn[t] - hv; }
    __syncthreads();

#pragma unroll
    for (int i = 0; i < 16; i++) {
        if (bks[i] >= 0) {
            int slot = atomicAdd(&cur[bks[i]], 1);
            ord[slot] = vals[i];
            obk[slot] = (ushort)bks[i];
        }
    }
    if (t < NBUCK && hv > 0) gb[t] = atomicAdd(&gcur[t], hv);
    __syncthreads();

    for (int s = t; s < cnt; s += 256) {
        int bb = obk[s];
        ebuf[gb[bb] + (s - loff[bb])] = ord[s];
    }
}

__global__ __launch_bounds__(256) void k_csr(const unsigned* __restrict__ ebuf,
                                             const int* __restrict__ boff,
                                             int* __restrict__ off_g,
                                             int* __restrict__ deg_g,
                                             int* __restrict__ ssrc) {
    __shared__ int sdeg[512];
    __shared__ int pr[256];
    __shared__ int lofs[512];
    __shared__ int scnt[512];
    const int b = blockIdx.x, t = threadIdx.x;
    const int node0 = b << 9;
    const int ebase = boff[b];
    const int ecnt = boff[b + 1] - ebase;

    sdeg[t] = 0; sdeg[t + 256] = 0;
    __syncthreads();
    for (int s = t; s < ecnt; s += 256)
        atomicAdd(&sdeg[ebuf[ebase + s] >> 17], 1);
    __syncthreads();

    int d0 = sdeg[2 * t], d1 = sdeg[2 * t + 1];
    pr[t] = d0 + d1;
    __syncthreads();
    for (int d = 1; d < 256; d <<= 1) {
        int a = (t >= d) ? pr[t - d] : 0;
        __syncthreads();
        pr[t] += a;
        __syncthreads();
    }
    int ex = pr[t] - d0 - d1;
    lofs[2 * t] = ex;
    lofs[2 * t + 1] = ex + d0;
    scnt[2 * t] = 0; scnt[2 * t + 1] = 0;
    int n0 = node0 + 2 * t, n1 = n0 + 1;
    if (n0 < NN) { off_g[n0] = ebase + ex;      deg_g[n0] = d0; }
    if (n1 < NN) { off_g[n1] = ebase + ex + d0; deg_g[n1] = d1; }
    __syncthreads();

    for (int s = t; s < ecnt; s += 256) {
        unsigned v = ebuf[ebase + s];
        int dl = v >> 17;
        int c = atomicAdd(&scnt[dl], 1);
        ssrc[ebase + lofs[dl] + c] = (int)(v & 0x1FFFFu);
    }
}

// ---------------- edge-balanced group partition (binary search) ----------------
__global__ __launch_bounds__(256) void k_split(const int* __restrict__ off,
                                               int* __restrict__ nsplit) {
    int g = blockIdx.x * 256 + threadIdx.x;
    if (g > NGRP) return;
    if (g == NGRP) { nsplit[NGRP] = NN; return; }
    long target = (long)g * NE / NGRP;
    int lo = 0, hi = NN;          // smallest n with off[n] >= target
    while (lo < hi) {
        int mid = (lo + hi) >> 1;
        if (off[mid] < (int)target) lo = mid + 1; else hi = mid;
    }
    nsplit[g] = lo;
}

// ---------------- prep: transpose+convert weights to bf16 ----------------
__global__ __launch_bounds__(256) void k_prep(const float* __restrict__ W,
                                              const float* __restrict__ fcW,
                                              ushort* __restrict__ Wt,
                                              ushort* __restrict__ fcWt) {
    int t = blockIdx.x * 256 + threadIdx.x;
    for (int i = t; i < DHID * DIN; i += gridDim.x * 256) {   // Wt[n][k]
        int n = i >> 8, k = i & 255;
        Wt[i] = f2bf(W[k * DHID + n]);
    }
    for (int i = t; i < NCLS * DHID; i += gridDim.x * 256) {  // fcWt[n][k]
        int n = i >> 7, k = i & 127;
        fcWt[i] = f2bf(fcW[k * NCLS + n]);
    }
}

// ---------------- GEMM1: featb = bf16(X) @ bf16(W), MFMA, pipelined ----------------
// Fused epilogue also computes el = feat@attn_l, er = feat@attn_r.
__global__ __launch_bounds__(256, 2) void gemm1(const float* __restrict__ X,
                                                const ushort* __restrict__ Wt,
                                                const float* __restrict__ attn_l,
                                                const float* __restrict__ attn_r,
                                                ushort* __restrict__ featb,
                                                float* __restrict__ el,
                                                float* __restrict__ er) {
    __shared__ ushort Xs[2][128 * 64];   // 2 x 16 KB, [row][k] swizzled
    __shared__ ushort Wl[2][128 * 64];   // 2 x 16 KB, [n][k] swizzled
    __shared__ float Al[DHID], Ar[DHID];
    const int t = threadIdx.x;
    const int row0 = blockIdx.x * 128;

    if (t < 128) { Al[t] = attn_l[t]; Ar[t] = attn_r[t]; }

    int srow[4], ske[4];
#pragma unroll
    for (int i = 0; i < 4; i++) {
        int o = i * 4096 + t * 16;
        int row = o >> 7;
        int bl = (o & 127) ^ ((row & 7) << 4);
        srow[i] = row;
        ske[i] = bl >> 1;
    }

    float4 xr[4][2];
    uint4  wr[4];

#pragma unroll
    for (int i = 0; i < 4; i++) {
        int grow = row0 + srow[i];
        if (grow < NN) {
            const float4* p = (const float4*)(X + (size_t)grow * DIN + ske[i]);
            xr[i][0] = p[0]; xr[i][1] = p[1];
        } else {
            xr[i][0] = make_float4(0.f, 0.f, 0.f, 0.f);
            xr[i][1] = make_float4(0.f, 0.f, 0.f, 0.f);
        }
        wr[i] = *(const uint4*)(Wt + (size_t)srow[i] * DIN + ske[i]);
    }
#pragma unroll
    for (int i = 0; i < 4; i++) {
        int o = i * 4096 + t * 16;
        ushort8v b;
        b[0] = f2bf(xr[i][0].x); b[1] = f2bf(xr[i][0].y);
        b[2] = f2bf(xr[i][0].z); b[3] = f2bf(xr[i][0].w);
        b[4] = f2bf(xr[i][1].x); b[5] = f2bf(xr[i][1].y);
        b[6] = f2bf(xr[i][1].z); b[7] = f2bf(xr[i][1].w);
        *(ushort8v*)((char*)&Xs[0][0] + o) = b;
        *(uint4*)((char*)&Wl[0][0] + o) = wr[i];
    }
    __syncthreads();

    const int w = t >> 6, lane = t & 63;
    const int rbase = w * 32;
    const int lcol = lane & 15;
    const int kgrp = (lane >> 4) * 16;

    f32x4 acc[2][8];
#pragma unroll
    for (int r = 0; r < 2; r++)
#pragma unroll
        for (int c = 0; c < 8; c++) acc[r][c] = (f32x4){0.f, 0.f, 0.f, 0.f};

    for (int c = 0; c < 4; c++) {
        const int buf = c & 1;
        if (c < 3) {
            int k0g = (c + 1) * 64;
#pragma unroll
            for (int i = 0; i < 4; i++) {
                int grow = row0 + srow[i];
                if (grow < NN) {
                    const float4* p = (const float4*)(X + (size_t)grow * DIN + k0g + ske[i]);
                    xr[i][0] = p[0]; xr[i][1] = p[1];
                } else {
                    xr[i][0] = make_float4(0.f, 0.f, 0.f, 0.f);
                    xr[i][1] = make_float4(0.f, 0.f, 0.f, 0.f);
                }
                wr[i] = *(const uint4*)(Wt + (size_t)srow[i] * DIN + k0g + ske[i]);
            }
        }
        const char* xb = (const char*)&Xs[buf][0];
        const char* wb = (const char*)&Wl[buf][0];
#pragma unroll
        for (int k0 = 0; k0 < 2; k0++) {
            int kb = k0 * 64 + kgrp;
            bf16x8 a[2], b[8];
#pragma unroll
            for (int r = 0; r < 2; r++) {
                int row = rbase + r * 16 + lcol;
                a[r] = *(const bf16x8*)(xb + row * 128 + (kb ^ ((row & 7) << 4)));
            }
#pragma unroll
            for (int cc = 0; cc < 8; cc++) {
                int n = cc * 16 + lcol;
                b[cc] = *(const bf16x8*)(wb + n * 128 + (kb ^ ((n & 7) << 4)));
            }
#pragma unroll
            for (int r = 0; r < 2; r++)
#pragma unroll
                for (int cc = 0; cc < 8; cc++)
                    acc[r][cc] = __builtin_amdgcn_mfma_f32_16x16x32_bf16(a[r], b[cc], acc[r][cc], 0, 0, 0);
        }
        if (c < 3) {
#pragma unroll
            for (int i = 0; i < 4; i++) {
                int o = i * 4096 + t * 16;
                ushort8v b;
                b[0] = f2bf(xr[i][0].x); b[1] = f2bf(xr[i][0].y);
                b[2] = f2bf(xr[i][0].z); b[3] = f2bf(xr[i][0].w);
                b[4] = f2bf(xr[i][1].x); b[5] = f2bf(xr[i][1].y);
                b[6] = f2bf(xr[i][1].z); b[7] = f2bf(xr[i][1].w);
                *(ushort8v*)((char*)&Xs[buf ^ 1][0] + o) = b;
                *(uint4*)((char*)&Wl[buf ^ 1][0] + o) = wr[i];
            }
        }
        __syncthreads();
    }

    // epilogue: stage bf16 tile (reuses Xs: 2*16KB = exactly 128x128 bf16)
    ushort* Os = (ushort*)Xs;
#pragma unroll
    for (int r = 0; r < 2; r++)
#pragma unroll
        for (int cc = 0; cc < 8; cc++)
#pragma unroll
            for (int i = 0; i < 4; i++) {
                int rloc = rbase + r * 16 + (lane >> 4) * 4 + i;
                int col = cc * 16 + lcol;
                Os[rloc * 128 + col] = f2bf(acc[r][cc][i]);
            }
    __syncthreads();

    // fused el/er: 2 threads per row, row-rotated LDS reads
    {
        int row = t >> 1, half = t & 1;
        int grow = row0 + row;
        const ushort* orow = Os + row * 128 + half * 64;
        const float* alp = Al + half * 64;
        const float* arp = Ar + half * 64;
        float pl = 0.f, pr = 0.f;
        int rot = row & 7;
#pragma unroll
        for (int qq = 0; qq < 8; qq++) {
            int q = (qq + rot) & 7;
            ushort8v f8 = *(const ushort8v*)(orow + q * 8);
#pragma unroll
            for (int e = 0; e < 8; e++) {
                float fe = bf2f(f8[e]);
                pl += fe * alp[q * 8 + e];
                pr += fe * arp[q * 8 + e];
            }
        }
        pl += __shfl_down(pl, 1);
        pr += __shfl_down(pr, 1);
        if (!half && grow < NN) { el[grow] = pl; er[grow] = pr; }
    }

#pragma unroll
    for (int i = 0; i < 8; i++) {
        int u = i * 256 + t;
        int row = u >> 4;
        int grow = row0 + row;
        if (grow < NN)
            *(uint4*)(featb + (size_t)grow * 128 + (u & 15) * 8) =
                *(uint4*)((char*)Os + u * 16);
    }
}

// ---------------- fused softmax + aggregate, v5 ----------------
// 16-lane group per node (lane owns 8 cols); edge-balanced node ranges.
// No max pass (exp range safe, shift-invariant softmax); no cross-lane
// reductions. 8 edges in flight per lane.
__global__ __launch_bounds__(256) void aggregate(const int* __restrict__ off,
                                                 const int* __restrict__ deg,
                                                 const int* __restrict__ ssrc,
                                                 const float* __restrict__ el,
                                                 const float* __restrict__ er,
                                                 const ushort* __restrict__ featb,
                                                 ushort* __restrict__ hb,
                                                 const int* __restrict__ nsplit) {
    const int gid = blockIdx.x * 16 + (threadIdx.x >> 4);
    const int lc = threadIdx.x & 15;
    int n = nsplit[gid];
    const int nend = nsplit[gid + 1];
    const ushort* fb = featb + lc * 8;

    for (; n < nend; ++n) {
        const int e0 = off[n];
        const int dg = deg[n];
        const float erd = er[n];
        float acc[8];
#pragma unroll
        for (int q = 0; q < 8; q++) acc[q] = 0.f;
        float wsum = 0.f;

        int j = 0;
        for (; j + 8 <= dg; j += 8) {
            int sv[8];
            ushort8v fv[8];
            float wv[8];
#pragma unroll
            for (int u = 0; u < 8; u++) sv[u] = ssrc[e0 + j + u];
#pragma unroll
            for (int u = 0; u < 8; u++)
                fv[u] = *(const ushort8v*)(fb + (size_t)sv[u] * DHID);
#pragma unroll
            for (int u = 0; u < 8; u++) {
                float x = el[sv[u]] + erd;
                x = x > 0.f ? x : NEG_SLOPE * x;
                wv[u] = __expf(x);
                wsum += wv[u];
            }
#pragma unroll
            for (int u = 0; u < 8; u++)
#pragma unroll
                for (int q = 0; q < 8; q++)
                    acc[q] += wv[u] * bf2f(fv[u][q]);
        }
        for (; j + 2 <= dg; j += 2) {
            int s0 = ssrc[e0 + j + 0];
            int s1 = ssrc[e0 + j + 1];
            ushort8v f0 = *(const ushort8v*)(fb + (size_t)s0 * DHID);
            ushort8v f1 = *(const ushort8v*)(fb + (size_t)s1 * DHID);
            float x0 = el[s0] + erd, x1 = el[s1] + erd;
            x0 = x0 > 0.f ? x0 : NEG_SLOPE * x0;
            x1 = x1 > 0.f ? x1 : NEG_SLOPE * x1;
            float w0 = __expf(x0), w1 = __expf(x1);
            wsum += w0 + w1;
#pragma unroll
            for (int q = 0; q < 8; q++)
                acc[q] += w0 * bf2f(f0[q]) + w1 * bf2f(f1[q]);
        }
        if (j < dg) {
            int s0 = ssrc[e0 + j];
            ushort8v f0 = *(const ushort8v*)(fb + (size_t)s0 * DHID);
            float x0 = el[s0] + erd;
            x0 = x0 > 0.f ? x0 : NEG_SLOPE * x0;
            float w0 = __expf(x0);
            wsum += w0;
#pragma unroll
            for (int q = 0; q < 8; q++) acc[q] += w0 * bf2f(f0[q]);
        }

        float inv = (dg > 0) ? 1.0f / wsum : 0.f;
        ushort8v o8;
#pragma unroll
        for (int q = 0; q < 8; q++) o8[q] = f2bf(acc[q] * inv);
        *(ushort8v*)(hb + (size_t)n * DHID + lc * 8) = o8;
    }
}

// ---------------- GEMM2: out = bf16(h) @ bf16(fcW) + fcb, MFMA ----------------
__global__ __launch_bounds__(256) void gemm2(const ushort* __restrict__ hb,
                                             const ushort* __restrict__ fcWt,
                                             const float* __restrict__ fcb,
                                             float* __restrict__ out) {
    __shared__ ushort Hs[128 * 128];
    __shared__ ushort Fs[64 * 128];
    __shared__ float  Os[128 * 64];
    const int t = threadIdx.x;
    const int row0 = blockIdx.x * 128;

    {
#pragma unroll
        for (int i = 0; i < 8; i++) {
            int u = i * 256 + t;
            int row = u >> 4;
            int grow = row0 + row;
            uint4 v = make_uint4(0, 0, 0, 0);
            if (grow < NN) v = *(const uint4*)(hb + (size_t)grow * 128 + (u & 15) * 8);
            int byte_off = row * 256 + (((u & 15) * 16) ^ ((row & 7) << 4));
            *(uint4*)((char*)Hs + byte_off) = v;
        }
#pragma unroll
        for (int i = 0; i < 4; i++) {
            int u = i * 256 + t;
            int n = u >> 4;
            int byte_off = n * 256 + (((u & 15) * 16) ^ ((n & 7) << 4));
            *(uint4*)((char*)Fs + byte_off) = ((const uint4*)fcWt)[u];
        }
    }
    __syncthreads();

    const int w = t >> 6, lane = t & 63;
    const int rbase = w * 32;
    const int lcol = lane & 15;
    const int kgrp = (lane >> 4) * 16;

    f32x4 acc[2][4];
#pragma unroll
    for (int r = 0; r < 2; r++)
#pragma unroll
        for (int c = 0; c < 4; c++) acc[r][c] = (f32x4){0.f, 0.f, 0.f, 0.f};

#pragma unroll
    for (int k0 = 0; k0 < 4; k0++) {
        int kbyte = k0 * 64 + kgrp;
        bf16x8 a[2], b[4];
#pragma unroll
        for (int r = 0; r < 2; r++) {
            int row = rbase + r * 16 + lcol;
            a[r] = *(bf16x8*)((char*)Hs + row * 256 + (kbyte ^ ((row & 7) << 4)));
        }
#pragma unroll
        for (int c = 0; c < 4; c++) {
            int n = c * 16 + lcol;
            b[c] = *(bf16x8*)((char*)Fs + n * 256 + (kbyte ^ ((n & 7) << 4)));
        }
#pragma unroll
        for (int r = 0; r < 2; r++)
#pragma unroll
            for (int c = 0; c < 4; c++)
                acc[r][c] = __builtin_amdgcn_mfma_f32_16x16x32_bf16(a[r], b[c], acc[r][c], 0, 0, 0);
    }

#pragma unroll
    for (int r = 0; r < 2; r++)
#pragma unroll
        for (int c = 0; c < 4; c++) {
            int col = c * 16 + lcol;
            float bias = fcb[col];
#pragma unroll
            for (int i = 0; i < 4; i++) {
                int rloc = rbase + r * 16 + (lane >> 4) * 4 + i;
                Os[rloc * 64 + col] = acc[r][c][i] + bias;
            }
        }
    __syncthreads();
#pragma unroll
    for (int i = 0; i < 8; i++) {
        int u = i * 256 + t;
        int row = u >> 4;
        int grow = row0 + row;
        if (grow < NN)
            *(float4*)(out + (size_t)grow * 64 + (u & 15) * 4) = ((float4*)Os)[u];
    }
}

// ---------------- launch ----------------
extern "C" void kernel_launch(void* const* d_in, const int* in_sizes, int n_in,
                              void* d_out, int out_size, void* d_ws, size_t ws_size,
                              hipStream_t stream) {
    const float* X      = (const float*)d_in[0];
    const float* W      = (const float*)d_in[1];
    const float* attn_l = (const float*)d_in[2];
    const float* attn_r = (const float*)d_in[3];
    const float* fcW    = (const float*)d_in[4];
    const float* fcb    = (const float*)d_in[5];
    const int*   src    = (const int*)d_in[6];
    const int*   dst    = (const int*)d_in[7];
    float* out = (float*)d_out;

    char* ws = (char*)d_ws;
    ushort* featb = (ushort*)ws;            ws += (size_t)NN * DHID * 2;
    ushort* hb    = (ushort*)ws;            ws += (size_t)NN * DHID * 2;
    ushort* Wt    = (ushort*)ws;            ws += (size_t)DHID * DIN * 2;
    ushort* fcWt  = (ushort*)ws;            ws += (size_t)NCLS * DHID * 2;
    float* el     = (float*)ws;             ws += (size_t)NN * 4;
    float* er     = (float*)ws;             ws += (size_t)NN * 4;
    int*   deg    = (int*)ws;               ws += (size_t)NN * 4;
    int*   off    = (int*)ws;               ws += (size_t)NN * 4;
    int*   ssrc   = (int*)ws;               ws += (size_t)NE * 4;
    unsigned* ebuf = (unsigned*)ws;         ws += (size_t)NE * 4;
    int*   ghist  = (int*)ws;               ws += (size_t)256 * 4;
    int*   boff   = (int*)ws;               ws += (size_t)256 * 4;
    int*   gcur   = (int*)ws;               ws += (size_t)256 * 4;
    int*   nsplit = (int*)ws;               ws += (size_t)(NGRP + 1) * 4;

    hipMemsetAsync(ghist, 0, NBUCK * sizeof(int), stream);

    // CSR build (bucketed counting sort)
    k_ghist<<<NCHB, 256, 0, stream>>>(dst, ghist);
    k_prep<<<64, 256, 0, stream>>>(W, fcW, Wt, fcWt);
    k_gscan<<<1, 256, 0, stream>>>(ghist, boff, gcur);
    k_bin<<<NCHB, 256, 0, stream>>>(src, dst, gcur, ebuf);
    k_csr<<<NBUCK, 256, 0, stream>>>(ebuf, boff, off, deg, ssrc);
    k_split<<<(NGRP + 256) / 256, 256, 0, stream>>>(off, nsplit);

    // dense pipeline (bf16 MFMA, el/er fused into gemm1 epilogue)
    gemm1<<<(NN + 127) / 128, 256, 0, stream>>>(X, Wt, attn_l, attn_r, featb, el, er);
    aggregate<<<NGRP / 16, 256, 0, stream>>>(off, deg, ssrc, el, er, featb, hb, nsplit);
    gemm2<<<(NN + 127) / 128, 256, 0, stream>>>(hb, fcWt, fcb, out);
}

// Round 9
// 173.090 us; speedup vs baseline: 1.1877x; 1.0750x over previous
//
#include <hip/hip_runtime.h>
#include <math.h>

#define NN 100000
#define NE 1600000
#define DIN 256
#define DHID 128
#define NCLS 64
#define NEG_SLOPE 0.2f

#define NBUCK 196          // ceil(NN / 512), bucket = dst >> 9
#define ECAP 10240         // fixed per-bucket ebuf capacity (mean 8192, +22 sigma)
#define CHUNK 4096
#define NCHB ((NE + CHUNK - 1) / CHUNK)   // 391

#define NGRP 16384         // edge-balanced 16-lane groups for aggregate

typedef __bf16 bf16_t;
typedef bf16_t bf16x8 __attribute__((ext_vector_type(8)));
typedef float f32x4 __attribute__((ext_vector_type(4)));
typedef ushort ushort8v __attribute__((ext_vector_type(8)));

__device__ __forceinline__ ushort f2bf(float f) {
    union { float f; unsigned u; } c; c.f = f;
    unsigned u = c.u;
    unsigned r = (u + 0x7FFFu + ((u >> 16) & 1u)) >> 16;
    return (ushort)r;
}
__device__ __forceinline__ float bf2f(ushort b) {
    return __uint_as_float(((unsigned)b) << 16);
}

// ================= CSR build: bucketed counting sort (fixed-capacity) =================
__global__ __launch_bounds__(256) void k_bin(const int* __restrict__ src,
                                             const int* __restrict__ dst,
                                             int* __restrict__ gcur,
                                             unsigned* __restrict__ ebuf) {
    __shared__ int hist[NBUCK];
    __shared__ int scn[256];
    __shared__ int loff[NBUCK];
    __shared__ int cur[NBUCK];
    __shared__ int gb[NBUCK];
    __shared__ unsigned ord[CHUNK];
    __shared__ ushort obk[CHUNK];
    const int t = threadIdx.x;
    const int base = blockIdx.x * CHUNK;
    int cnt = NE - base; if (cnt > CHUNK) cnt = CHUNK;

    for (int i = t; i < NBUCK; i += 256) hist[i] = 0;
    __syncthreads();

    unsigned vals[16];
    int bks[16];
#pragma unroll
    for (int i = 0; i < 16; i++) {
        int idx = base + i * 256 + t;
        if (idx < NE) {
            int d = dst[idx], s = src[idx];
            int bb = d >> 9;
            bks[i] = bb;
            vals[i] = ((unsigned)(d & 511) << 17) | (unsigned)s;
            atomicAdd(&hist[bb], 1);
        } else bks[i] = -1;
    }
    __syncthreads();

    int hv = (t < NBUCK) ? hist[t] : 0;
    scn[t] = hv;
    __syncthreads();
    for (int d = 1; d < 256; d <<= 1) {
        int a = (t >= d) ? scn[t - d] : 0;
        __syncthreads();
        scn[t] += a;
        __syncthreads();
    }
    if (t < NBUCK) { loff[t] = scn[t] - hv; cur[t] = scn[t] - hv; }
    __syncthreads();

#pragma unroll
    for (int i = 0; i < 16; i++) {
        if (bks[i] >= 0) {
            int slot = atomicAdd(&cur[bks[i]], 1);
            ord[slot] = vals[i];
            obk[slot] = (ushort)bks[i];
        }
    }
    if (t < NBUCK && hv > 0) gb[t] = t * ECAP + atomicAdd(&gcur[t], hv);
    __syncthreads();

    for (int s = t; s < cnt; s += 256) {
        int bb = obk[s];
        ebuf[gb[bb] + (s - loff[bb])] = ord[s];
    }
}

// one block per bucket: per-node deg/offsets in LDS, local scatter
__global__ __launch_bounds__(256) void k_csr(const unsigned* __restrict__ ebuf,
                                             const int* __restrict__ gcur,
                                             int* __restrict__ off_g,
                                             int* __restrict__ deg_g,
                                             int* __restrict__ ssrc) {
    __shared__ int sdeg[512];
    __shared__ int pr[256];
    __shared__ int lofs[512];
    __shared__ int scnt[512];
    const int b = blockIdx.x, t = threadIdx.x;
    const int node0 = b << 9;
    const int ebase = b * ECAP;
    const int ecnt = gcur[b];

    sdeg[t] = 0; sdeg[t + 256] = 0;
    __syncthreads();
    for (int s = t; s < ecnt; s += 256)
        atomicAdd(&sdeg[ebuf[ebase + s] >> 17], 1);
    __syncthreads();

    int d0 = sdeg[2 * t], d1 = sdeg[2 * t + 1];
    pr[t] = d0 + d1;
    __syncthreads();
    for (int d = 1; d < 256; d <<= 1) {
        int a = (t >= d) ? pr[t - d] : 0;
        __syncthreads();
        pr[t] += a;
        __syncthreads();
    }
    int ex = pr[t] - d0 - d1;
    lofs[2 * t] = ex;
    lofs[2 * t + 1] = ex + d0;
    scnt[2 * t] = 0; scnt[2 * t + 1] = 0;
    int n0 = node0 + 2 * t, n1 = n0 + 1;
    if (n0 < NN) { off_g[n0] = ebase + ex;      deg_g[n0] = d0; }
    if (n1 < NN) { off_g[n1] = ebase + ex + d0; deg_g[n1] = d1; }
    __syncthreads();

    for (int s = t; s < ecnt; s += 256) {
        unsigned v = ebuf[ebase + s];
        int dl = v >> 17;
        int c = atomicAdd(&scnt[dl], 1);
        ssrc[ebase + lofs[dl] + c] = (int)(v & 0x1FFFFu);
    }
}

// ---------------- edge-balanced group partition (binary search) ----------------
// off spans [0, NBUCK*ECAP) with gaps; targets scaled to the padded span.
__global__ __launch_bounds__(256) void k_split(const int* __restrict__ off,
                                               int* __restrict__ nsplit) {
    int g = blockIdx.x * 256 + threadIdx.x;
    if (g > NGRP) return;
    if (g == NGRP) { nsplit[NGRP] = NN; return; }
    long span = (long)NBUCK * ECAP;
    long target = (long)g * span / NGRP;
    int lo = 0, hi = NN;          // smallest n with off[n] >= target
    while (lo < hi) {
        int mid = (lo + hi) >> 1;
        if ((long)off[mid] < target) lo = mid + 1; else hi = mid;
    }
    nsplit[g] = lo;
}

// ---------------- prep: transpose+convert weights to bf16 ----------------
__global__ __launch_bounds__(256) void k_prep(const float* __restrict__ W,
                                              const float* __restrict__ fcW,
                                              ushort* __restrict__ Wt,
                                              ushort* __restrict__ fcWt) {
    int t = blockIdx.x * 256 + threadIdx.x;
    for (int i = t; i < DHID * DIN; i += gridDim.x * 256) {   // Wt[n][k]
        int n = i >> 8, k = i & 255;
        Wt[i] = f2bf(W[k * DHID + n]);
    }
    for (int i = t; i < NCLS * DHID; i += gridDim.x * 256) {  // fcWt[n][k]
        int n = i >> 7, k = i & 127;
        fcWt[i] = f2bf(fcW[k * NCLS + n]);
    }
}

// ---------------- GEMM1: featb = bf16(X) @ bf16(W), MFMA, pipelined ----------------
// Fused epilogue also computes el = feat@attn_l, er = feat@attn_r.
__global__ __launch_bounds__(256, 2) void gemm1(const float* __restrict__ X,
                                                const ushort* __restrict__ Wt,
                                                const float* __restrict__ attn_l,
                                                const float* __restrict__ attn_r,
                                                ushort* __restrict__ featb,
                                                float* __restrict__ el,
                                                float* __restrict__ er) {
    __shared__ ushort Xs[2][128 * 64];   // 2 x 16 KB, [row][k] swizzled
    __shared__ ushort Wl[2][128 * 64];   // 2 x 16 KB, [n][k] swizzled
    __shared__ float Al[DHID], Ar[DHID];
    const int t = threadIdx.x;
    const int row0 = blockIdx.x * 128;

    if (t < 128) { Al[t] = attn_l[t]; Ar[t] = attn_r[t]; }

    int srow[4], ske[4];
#pragma unroll
    for (int i = 0; i < 4; i++) {
        int o = i * 4096 + t * 16;
        int row = o >> 7;
        int bl = (o & 127) ^ ((row & 7) << 4);
        srow[i] = row;
        ske[i] = bl >> 1;
    }

    float4 xr[4][2];
    uint4  wr[4];

#pragma unroll
    for (int i = 0; i < 4; i++) {
        int grow = row0 + srow[i];
        if (grow < NN) {
            const float4* p = (const float4*)(X + (size_t)grow * DIN + ske[i]);
            xr[i][0] = p[0]; xr[i][1] = p[1];
        } else {
            xr[i][0] = make_float4(0.f, 0.f, 0.f, 0.f);
            xr[i][1] = make_float4(0.f, 0.f, 0.f, 0.f);
        }
        wr[i] = *(const uint4*)(Wt + (size_t)srow[i] * DIN + ske[i]);
    }
#pragma unroll
    for (int i = 0; i < 4; i++) {
        int o = i * 4096 + t * 16;
        ushort8v b;
        b[0] = f2bf(xr[i][0].x); b[1] = f2bf(xr[i][0].y);
        b[2] = f2bf(xr[i][0].z); b[3] = f2bf(xr[i][0].w);
        b[4] = f2bf(xr[i][1].x); b[5] = f2bf(xr[i][1].y);
        b[6] = f2bf(xr[i][1].z); b[7] = f2bf(xr[i][1].w);
        *(ushort8v*)((char*)&Xs[0][0] + o) = b;
        *(uint4*)((char*)&Wl[0][0] + o) = wr[i];
    }
    __syncthreads();

    const int w = t >> 6, lane = t & 63;
    const int rbase = w * 32;
    const int lcol = lane & 15;
    const int kgrp = (lane >> 4) * 16;

    f32x4 acc[2][8];
#pragma unroll
    for (int r = 0; r < 2; r++)
#pragma unroll
        for (int c = 0; c < 8; c++) acc[r][c] = (f32x4){0.f, 0.f, 0.f, 0.f};

    for (int c = 0; c < 4; c++) {
        const int buf = c & 1;
        if (c < 3) {
            int k0g = (c + 1) * 64;
#pragma unroll
            for (int i = 0; i < 4; i++) {
                int grow = row0 + srow[i];
                if (grow < NN) {
                    const float4* p = (const float4*)(X + (size_t)grow * DIN + k0g + ske[i]);
                    xr[i][0] = p[0]; xr[i][1] = p[1];
                } else {
                    xr[i][0] = make_float4(0.f, 0.f, 0.f, 0.f);
                    xr[i][1] = make_float4(0.f, 0.f, 0.f, 0.f);
                }
                wr[i] = *(const uint4*)(Wt + (size_t)srow[i] * DIN + k0g + ske[i]);
            }
        }
        const char* xb = (const char*)&Xs[buf][0];
        const char* wb = (const char*)&Wl[buf][0];
#pragma unroll
        for (int k0 = 0; k0 < 2; k0++) {
            int kb = k0 * 64 + kgrp;
            bf16x8 a[2], b[8];
#pragma unroll
            for (int r = 0; r < 2; r++) {
                int row = rbase + r * 16 + lcol;
                a[r] = *(const bf16x8*)(xb + row * 128 + (kb ^ ((row & 7) << 4)));
            }
#pragma unroll
            for (int cc = 0; cc < 8; cc++) {
                int n = cc * 16 + lcol;
                b[cc] = *(const bf16x8*)(wb + n * 128 + (kb ^ ((n & 7) << 4)));
            }
#pragma unroll
            for (int r = 0; r < 2; r++)
#pragma unroll
                for (int cc = 0; cc < 8; cc++)
                    acc[r][cc] = __builtin_amdgcn_mfma_f32_16x16x32_bf16(a[r], b[cc], acc[r][cc], 0, 0, 0);
        }
        if (c < 3) {
#pragma unroll
            for (int i = 0; i < 4; i++) {
                int o = i * 4096 + t * 16;
                ushort8v b;
                b[0] = f2bf(xr[i][0].x); b[1] = f2bf(xr[i][0].y);
                b[2] = f2bf(xr[i][0].z); b[3] = f2bf(xr[i][0].w);
                b[4] = f2bf(xr[i][1].x); b[5] = f2bf(xr[i][1].y);
                b[6] = f2bf(xr[i][1].z); b[7] = f2bf(xr[i][1].w);
                *(ushort8v*)((char*)&Xs[buf ^ 1][0] + o) = b;
                *(uint4*)((char*)&Wl[buf ^ 1][0] + o) = wr[i];
            }
        }
        __syncthreads();
    }

    // epilogue: stage bf16 tile (reuses Xs: 2*16KB = exactly 128x128 bf16)
    ushort* Os = (ushort*)Xs;
#pragma unroll
    for (int r = 0; r < 2; r++)
#pragma unroll
        for (int cc = 0; cc < 8; cc++)
#pragma unroll
            for (int i = 0; i < 4; i++) {
                int rloc = rbase + r * 16 + (lane >> 4) * 4 + i;
                int col = cc * 16 + lcol;
                Os[rloc * 128 + col] = f2bf(acc[r][cc][i]);
            }
    __syncthreads();

    // fused el/er: 2 threads per row, row-rotated LDS reads
    {
        int row = t >> 1, half = t & 1;
        int grow = row0 + row;
        const ushort* orow = Os + row * 128 + half * 64;
        const float* alp = Al + half * 64;
        const float* arp = Ar + half * 64;
        float pl = 0.f, pr = 0.f;
        int rot = row & 7;
#pragma unroll
        for (int qq = 0; qq < 8; qq++) {
            int q = (qq + rot) & 7;
            ushort8v f8 = *(const ushort8v*)(orow + q * 8);
#pragma unroll
            for (int e = 0; e < 8; e++) {
                float fe = bf2f(f8[e]);
                pl += fe * alp[q * 8 + e];
                pr += fe * arp[q * 8 + e];
            }
        }
        pl += __shfl_down(pl, 1);
        pr += __shfl_down(pr, 1);
        if (!half && grow < NN) { el[grow] = pl; er[grow] = pr; }
    }

#pragma unroll
    for (int i = 0; i < 8; i++) {
        int u = i * 256 + t;
        int row = u >> 4;
        int grow = row0 + row;
        if (grow < NN)
            *(uint4*)(featb + (size_t)grow * 128 + (u & 15) * 8) =
                *(uint4*)((char*)Os + u * 16);
    }
}

// ---------------- fused softmax + aggregate (R7 known-good config) ----------------
__global__ __launch_bounds__(256) void aggregate(const int* __restrict__ off,
                                                 const int* __restrict__ deg,
                                                 const int* __restrict__ ssrc,
                                                 const float* __restrict__ el,
                                                 const float* __restrict__ er,
                                                 const ushort* __restrict__ featb,
                                                 ushort* __restrict__ hb,
                                                 const int* __restrict__ nsplit) {
    const int gid = blockIdx.x * 16 + (threadIdx.x >> 4);
    const int lc = threadIdx.x & 15;
    int n = nsplit[gid];
    const int nend = nsplit[gid + 1];
    const ushort* fb = featb + lc * 8;

    for (; n < nend; ++n) {
        const int e0 = off[n];
        const int dg = deg[n];
        const float erd = er[n];
        float acc[8];
#pragma unroll
        for (int q = 0; q < 8; q++) acc[q] = 0.f;
        float wsum = 0.f;

        int j = 0;
        for (; j + 4 <= dg; j += 4) {
            int s0 = ssrc[e0 + j + 0];
            int s1 = ssrc[e0 + j + 1];
            int s2 = ssrc[e0 + j + 2];
            int s3 = ssrc[e0 + j + 3];
            ushort8v f0 = *(const ushort8v*)(fb + (size_t)s0 * DHID);
            ushort8v f1 = *(const ushort8v*)(fb + (size_t)s1 * DHID);
            ushort8v f2 = *(const ushort8v*)(fb + (size_t)s2 * DHID);
            ushort8v f3 = *(const ushort8v*)(fb + (size_t)s3 * DHID);
            float x0 = el[s0] + erd, x1 = el[s1] + erd;
            float x2 = el[s2] + erd, x3 = el[s3] + erd;
            x0 = x0 > 0.f ? x0 : NEG_SLOPE * x0;
            x1 = x1 > 0.f ? x1 : NEG_SLOPE * x1;
            x2 = x2 > 0.f ? x2 : NEG_SLOPE * x2;
            x3 = x3 > 0.f ? x3 : NEG_SLOPE * x3;
            float w0 = __expf(x0), w1 = __expf(x1);
            float w2 = __expf(x2), w3 = __expf(x3);
            wsum += (w0 + w1) + (w2 + w3);
#pragma unroll
            for (int q = 0; q < 8; q++)
                acc[q] += (w0 * bf2f(f0[q]) + w1 * bf2f(f1[q])) +
                          (w2 * bf2f(f2[q]) + w3 * bf2f(f3[q]));
        }
        for (; j < dg; ++j) {
            int s0 = ssrc[e0 + j];
            ushort8v f0 = *(const ushort8v*)(fb + (size_t)s0 * DHID);
            float x0 = el[s0] + erd;
            x0 = x0 > 0.f ? x0 : NEG_SLOPE * x0;
            float w0 = __expf(x0);
            wsum += w0;
#pragma unroll
            for (int q = 0; q < 8; q++) acc[q] += w0 * bf2f(f0[q]);
        }

        float inv = (dg > 0) ? 1.0f / wsum : 0.f;
        ushort8v o8;
#pragma unroll
        for (int q = 0; q < 8; q++) o8[q] = f2bf(acc[q] * inv);
        *(ushort8v*)(hb + (size_t)n * DHID + lc * 8) = o8;
    }
}

// ---------------- GEMM2: out = bf16(h) @ bf16(fcW) + fcb, MFMA, direct store ----------------
__global__ __launch_bounds__(256) void gemm2(const ushort* __restrict__ hb,
                                             const ushort* __restrict__ fcWt,
                                             const float* __restrict__ fcb,
                                             float* __restrict__ out) {
    __shared__ ushort Hs[128 * 128];   // 32 KB
    __shared__ ushort Fs[64 * 128];    // 16 KB
    const int t = threadIdx.x;
    const int row0 = blockIdx.x * 128;

    {
#pragma unroll
        for (int i = 0; i < 8; i++) {
            int u = i * 256 + t;
            int row = u >> 4;
            int grow = row0 + row;
            uint4 v = make_uint4(0, 0, 0, 0);
            if (grow < NN) v = *(const uint4*)(hb + (size_t)grow * 128 + (u & 15) * 8);
            int byte_off = row * 256 + (((u & 15) * 16) ^ ((row & 7) << 4));
            *(uint4*)((char*)Hs + byte_off) = v;
        }
#pragma unroll
        for (int i = 0; i < 4; i++) {
            int u = i * 256 + t;
            int n = u >> 4;
            int byte_off = n * 256 + (((u & 15) * 16) ^ ((n & 7) << 4));
            *(uint4*)((char*)Fs + byte_off) = ((const uint4*)fcWt)[u];
        }
    }

    const int w = t >> 6, lane = t & 63;
    const int rbase = w * 32;
    const int lcol = lane & 15;
    const int kgrp = (lane >> 4) * 16;

    f32x4 acc[2][4];
#pragma unroll
    for (int c = 0; c < 4; c++) {
        float bias = fcb[c * 16 + lcol];
#pragma unroll
        for (int r = 0; r < 2; r++)
#pragma unroll
            for (int i = 0; i < 4; i++) acc[r][c][i] = bias;
    }
    __syncthreads();

#pragma unroll
    for (int k0 = 0; k0 < 4; k0++) {
        int kbyte = k0 * 64 + kgrp;
        bf16x8 a[2], b[4];
#pragma unroll
        for (int r = 0; r < 2; r++) {
            int row = rbase + r * 16 + lcol;
            a[r] = *(bf16x8*)((char*)Hs + row * 256 + (kbyte ^ ((row & 7) << 4)));
        }
#pragma unroll
        for (int c = 0; c < 4; c++) {
            int n = c * 16 + lcol;
            b[c] = *(bf16x8*)((char*)Fs + n * 256 + (kbyte ^ ((n & 7) << 4)));
        }
#pragma unroll
        for (int r = 0; r < 2; r++)
#pragma unroll
            for (int c = 0; c < 4; c++)
                acc[r][c] = __builtin_amdgcn_mfma_f32_16x16x32_bf16(a[r], b[c], acc[r][c], 0, 0, 0);
    }

    // direct store: per (r,c,i) lanes 0-15 write 64B contiguous
#pragma unroll
    for (int r = 0; r < 2; r++)
#pragma unroll
        for (int i = 0; i < 4; i++) {
            int row = rbase + r * 16 + (lane >> 4) * 4 + i;
            int grow = row0 + row;
            if (grow < NN) {
                float* op = out + (size_t)grow * 64 + lcol;
#pragma unroll
                for (int c = 0; c < 4; c++) op[c * 16] = acc[r][c][i];
            }
        }
}

// ---------------- launch ----------------
extern "C" void kernel_launch(void* const* d_in, const int* in_sizes, int n_in,
                              void* d_out, int out_size, void* d_ws, size_t ws_size,
                              hipStream_t stream) {
    const float* X      = (const float*)d_in[0];
    const float* W      = (const float*)d_in[1];
    const float* attn_l = (const float*)d_in[2];
    const float* attn_r = (const float*)d_in[3];
    const float* fcW    = (const float*)d_in[4];
    const float* fcb    = (const float*)d_in[5];
    const int*   src    = (const int*)d_in[6];
    const int*   dst    = (const int*)d_in[7];
    float* out = (float*)d_out;

    char* ws = (char*)d_ws;
    ushort* featb = (ushort*)ws;            ws += (size_t)NN * DHID * 2;
    ushort* hb    = (ushort*)ws;            ws += (size_t)NN * DHID * 2;
    ushort* Wt    = (ushort*)ws;            ws += (size_t)DHID * DIN * 2;
    ushort* fcWt  = (ushort*)ws;            ws += (size_t)NCLS * DHID * 2;
    float* el     = (float*)ws;             ws += (size_t)NN * 4;
    float* er     = (float*)ws;             ws += (size_t)NN * 4;
    int*   deg    = (int*)ws;               ws += (size_t)NN * 4;
    int*   off    = (int*)ws;               ws += (size_t)NN * 4;
    int*   ssrc   = (int*)ws;               ws += (size_t)NBUCK * ECAP * 4;
    unsigned* ebuf = (unsigned*)ws;         ws += (size_t)NBUCK * ECAP * 4;
    int*   gcur   = (int*)ws;               ws += (size_t)256 * 4;
    int*   nsplit = (int*)ws;               ws += (size_t)(NGRP + 1) * 4;

    hipMemsetAsync(gcur, 0, NBUCK * sizeof(int), stream);

    // CSR build (fixed-capacity bucketed counting sort)
    k_prep<<<64, 256, 0, stream>>>(W, fcW, Wt, fcWt);
    k_bin<<<NCHB, 256, 0, stream>>>(src, dst, gcur, ebuf);
    k_csr<<<NBUCK, 256, 0, stream>>>(ebuf, gcur, off, deg, ssrc);
    k_split<<<(NGRP + 256) / 256, 256, 0, stream>>>(off, nsplit);

    // dense pipeline (bf16 MFMA, el/er fused into gemm1 epilogue)
    gemm1<<<(NN + 127) / 128, 256, 0, stream>>>(X, Wt, attn_l, attn_r, featb, el, er);
    aggregate<<<NGRP / 16, 256, 0, stream>>>(off, deg, ssrc, el, er, featb, hb, nsplit);
    gemm2<<<(NN + 127) / 128, 256, 0, stream>>>(hb, fcWt, fcb, out);
}

// Round 10
// 172.820 us; speedup vs baseline: 1.1896x; 1.0016x over previous
//
#include <hip/hip_runtime.h>
#include <math.h>

#define NN 100000
#define NE 1600000
#define DIN 256
#define DHID 128
#define NCLS 64
#define NEG_SLOPE 0.2f

#define NBUCK 196          // ceil(NN / 512), bucket = dst >> 9
#define ECAP 10240         // fixed per-bucket ebuf capacity (mean 8192, +22 sigma)
#define CHUNK 4096
#define NCHB ((NE + CHUNK - 1) / CHUNK)   // 391

#define NGRP 32768         // edge-balanced 16-lane groups for aggregate

typedef __bf16 bf16_t;
typedef bf16_t bf16x8 __attribute__((ext_vector_type(8)));
typedef float f32x4 __attribute__((ext_vector_type(4)));
typedef ushort ushort8v __attribute__((ext_vector_type(8)));

__device__ __forceinline__ ushort f2bf(float f) {
    union { float f; unsigned u; } c; c.f = f;
    unsigned u = c.u;
    unsigned r = (u + 0x7FFFu + ((u >> 16) & 1u)) >> 16;
    return (ushort)r;
}
__device__ __forceinline__ float bf2f(ushort b) {
    return __uint_as_float(((unsigned)b) << 16);
}

// ================= CSR build: bucketed counting sort (fixed-capacity) =================
__global__ __launch_bounds__(256) void k_bin(const int* __restrict__ src,
                                             const int* __restrict__ dst,
                                             int* __restrict__ gcur,
                                             unsigned* __restrict__ ebuf) {
    __shared__ int hist[NBUCK];
    __shared__ int scn[256];
    __shared__ int loff[NBUCK];
    __shared__ int cur[NBUCK];
    __shared__ int gb[NBUCK];
    __shared__ unsigned ord[CHUNK];
    __shared__ ushort obk[CHUNK];
    const int t = threadIdx.x;
    const int base = blockIdx.x * CHUNK;
    int cnt = NE - base; if (cnt > CHUNK) cnt = CHUNK;

    for (int i = t; i < NBUCK; i += 256) hist[i] = 0;
    __syncthreads();

    unsigned vals[16];
    int bks[16];
#pragma unroll
    for (int i = 0; i < 16; i++) {
        int idx = base + i * 256 + t;
        if (idx < NE) {
            int d = dst[idx], s = src[idx];
            int bb = d >> 9;
            bks[i] = bb;
            vals[i] = ((unsigned)(d & 511) << 17) | (unsigned)s;
            atomicAdd(&hist[bb], 1);
        } else bks[i] = -1;
    }
    __syncthreads();

    int hv = (t < NBUCK) ? hist[t] : 0;
    scn[t] = hv;
    __syncthreads();
    for (int d = 1; d < 256; d <<= 1) {
        int a = (t >= d) ? scn[t - d] : 0;
        __syncthreads();
        scn[t] += a;
        __syncthreads();
    }
    if (t < NBUCK) { loff[t] = scn[t] - hv; cur[t] = scn[t] - hv; }
    __syncthreads();

#pragma unroll
    for (int i = 0; i < 16; i++) {
        if (bks[i] >= 0) {
            int slot = atomicAdd(&cur[bks[i]], 1);
            ord[slot] = vals[i];
            obk[slot] = (ushort)bks[i];
        }
    }
    if (t < NBUCK && hv > 0) gb[t] = t * ECAP + atomicAdd(&gcur[t], hv);
    __syncthreads();

    for (int s = t; s < cnt; s += 256) {
        int bb = obk[s];
        ebuf[gb[bb] + (s - loff[bb])] = ord[s];
    }
}

// one block per bucket: per-node deg/offsets in LDS, local scatter
__global__ __launch_bounds__(256) void k_csr(const unsigned* __restrict__ ebuf,
                                             const int* __restrict__ gcur,
                                             int* __restrict__ off_g,
                                             int* __restrict__ deg_g,
                                             int* __restrict__ ssrc) {
    __shared__ int sdeg[512];
    __shared__ int pr[256];
    __shared__ int lofs[512];
    __shared__ int scnt[512];
    const int b = blockIdx.x, t = threadIdx.x;
    const int node0 = b << 9;
    const int ebase = b * ECAP;
    const int ecnt = gcur[b];

    sdeg[t] = 0; sdeg[t + 256] = 0;
    __syncthreads();
    for (int s = t; s < ecnt; s += 256)
        atomicAdd(&sdeg[ebuf[ebase + s] >> 17], 1);
    __syncthreads();

    int d0 = sdeg[2 * t], d1 = sdeg[2 * t + 1];
    pr[t] = d0 + d1;
    __syncthreads();
    for (int d = 1; d < 256; d <<= 1) {
        int a = (t >= d) ? pr[t - d] : 0;
        __syncthreads();
        pr[t] += a;
        __syncthreads();
    }
    int ex = pr[t] - d0 - d1;
    lofs[2 * t] = ex;
    lofs[2 * t + 1] = ex + d0;
    scnt[2 * t] = 0; scnt[2 * t + 1] = 0;
    int n0 = node0 + 2 * t, n1 = n0 + 1;
    if (n0 < NN) { off_g[n0] = ebase + ex;      deg_g[n0] = d0; }
    if (n1 < NN) { off_g[n1] = ebase + ex + d0; deg_g[n1] = d1; }
    __syncthreads();

    for (int s = t; s < ecnt; s += 256) {
        unsigned v = ebuf[ebase + s];
        int dl = v >> 17;
        int c = atomicAdd(&scnt[dl], 1);
        ssrc[ebase + lofs[dl] + c] = (int)(v & 0x1FFFFu);
    }
}

// ---------------- real-edge prefix over buckets ----------------
__global__ void k_bpre(const int* __restrict__ gcur, int* __restrict__ bpre) {
    __shared__ int sh[256];
    int t = threadIdx.x;
    int v = (t < NBUCK) ? gcur[t] : 0;
    sh[t] = v;
    __syncthreads();
    for (int d = 1; d < 256; d <<= 1) {
        int a = (t >= d) ? sh[t - d] : 0;
        __syncthreads();
        sh[t] += a;
        __syncthreads();
    }
    if (t < NBUCK) bpre[t] = sh[t] - v;
    if (t == NBUCK - 1) bpre[NBUCK] = sh[t];
}

// ---------------- edge-balanced group partition (binary search, exact) ----------------
// real edge coordinate of node n: off[n] - (n>>9)*ECAP + bpre[n>>9]  (monotone)
__global__ __launch_bounds__(256) void k_split(const int* __restrict__ off,
                                               const int* __restrict__ bpre,
                                               int* __restrict__ nsplit) {
    int g = blockIdx.x * 256 + threadIdx.x;
    if (g > NGRP) return;
    if (g == NGRP) { nsplit[NGRP] = NN; return; }
    long total = bpre[NBUCK];
    long target = (long)g * total / NGRP;
    int lo = 0, hi = NN;          // smallest n with real(n) >= target
    while (lo < hi) {
        int mid = (lo + hi) >> 1;
        int b = mid >> 9;
        long real = (long)off[mid] - (long)b * ECAP + bpre[b];
        if (real < target) lo = mid + 1; else hi = mid;
    }
    nsplit[g] = lo;
}

// ---------------- prep: transpose+convert weights to bf16 ----------------
__global__ __launch_bounds__(256) void k_prep(const float* __restrict__ W,
                                              const float* __restrict__ fcW,
                                              ushort* __restrict__ Wt,
                                              ushort* __restrict__ fcWt) {
    int t = blockIdx.x * 256 + threadIdx.x;
    for (int i = t; i < DHID * DIN; i += gridDim.x * 256) {   // Wt[n][k]
        int n = i >> 8, k = i & 255;
        Wt[i] = f2bf(W[k * DHID + n]);
    }
    for (int i = t; i < NCLS * DHID; i += gridDim.x * 256) {  // fcWt[n][k]
        int n = i >> 7, k = i & 127;
        fcWt[i] = f2bf(fcW[k * NCLS + n]);
    }
}

// ---------------- GEMM1: featb = bf16(X) @ bf16(W), MFMA, pipelined ----------------
// Fused epilogue also computes el = feat@attn_l, er = feat@attn_r.
__global__ __launch_bounds__(256, 2) void gemm1(const float* __restrict__ X,
                                                const ushort* __restrict__ Wt,
                                                const float* __restrict__ attn_l,
                                                const float* __restrict__ attn_r,
                                                ushort* __restrict__ featb,
                                                float* __restrict__ el,
                                                float* __restrict__ er) {
    __shared__ ushort Xs[2][128 * 64];   // 2 x 16 KB, [row][k] swizzled
    __shared__ ushort Wl[2][128 * 64];   // 2 x 16 KB, [n][k] swizzled
    __shared__ float Al[DHID], Ar[DHID];
    const int t = threadIdx.x;
    const int row0 = blockIdx.x * 128;

    if (t < 128) { Al[t] = attn_l[t]; Ar[t] = attn_r[t]; }

    int srow[4], ske[4];
#pragma unroll
    for (int i = 0; i < 4; i++) {
        int o = i * 4096 + t * 16;
        int row = o >> 7;
        int bl = (o & 127) ^ ((row & 7) << 4);
        srow[i] = row;
        ske[i] = bl >> 1;
    }

    float4 xr[4][2];
    uint4  wr[4];

#pragma unroll
    for (int i = 0; i < 4; i++) {
        int grow = row0 + srow[i];
        if (grow < NN) {
            const float4* p = (const float4*)(X + (size_t)grow * DIN + ske[i]);
            xr[i][0] = p[0]; xr[i][1] = p[1];
        } else {
            xr[i][0] = make_float4(0.f, 0.f, 0.f, 0.f);
            xr[i][1] = make_float4(0.f, 0.f, 0.f, 0.f);
        }
        wr[i] = *(const uint4*)(Wt + (size_t)srow[i] * DIN + ske[i]);
    }
#pragma unroll
    for (int i = 0; i < 4; i++) {
        int o = i * 4096 + t * 16;
        ushort8v b;
        b[0] = f2bf(xr[i][0].x); b[1] = f2bf(xr[i][0].y);
        b[2] = f2bf(xr[i][0].z); b[3] = f2bf(xr[i][0].w);
        b[4] = f2bf(xr[i][1].x); b[5] = f2bf(xr[i][1].y);
        b[6] = f2bf(xr[i][1].z); b[7] = f2bf(xr[i][1].w);
        *(ushort8v*)((char*)&Xs[0][0] + o) = b;
        *(uint4*)((char*)&Wl[0][0] + o) = wr[i];
    }
    __syncthreads();

    const int w = t >> 6, lane = t & 63;
    const int rbase = w * 32;
    const int lcol = lane & 15;
    const int kgrp = (lane >> 4) * 16;

    f32x4 acc[2][8];
#pragma unroll
    for (int r = 0; r < 2; r++)
#pragma unroll
        for (int c = 0; c < 8; c++) acc[r][c] = (f32x4){0.f, 0.f, 0.f, 0.f};

    for (int c = 0; c < 4; c++) {
        const int buf = c & 1;
        if (c < 3) {
            int k0g = (c + 1) * 64;
#pragma unroll
            for (int i = 0; i < 4; i++) {
                int grow = row0 + srow[i];
                if (grow < NN) {
                    const float4* p = (const float4*)(X + (size_t)grow * DIN + k0g + ske[i]);
                    xr[i][0] = p[0]; xr[i][1] = p[1];
                } else {
                    xr[i][0] = make_float4(0.f, 0.f, 0.f, 0.f);
                    xr[i][1] = make_float4(0.f, 0.f, 0.f, 0.f);
                }
                wr[i] = *(const uint4*)(Wt + (size_t)srow[i] * DIN + k0g + ske[i]);
            }
        }
        const char* xb = (const char*)&Xs[buf][0];
        const char* wb = (const char*)&Wl[buf][0];
#pragma unroll
        for (int k0 = 0; k0 < 2; k0++) {
            int kb = k0 * 64 + kgrp;
            bf16x8 a[2], b[8];
#pragma unroll
            for (int r = 0; r < 2; r++) {
                int row = rbase + r * 16 + lcol;
                a[r] = *(const bf16x8*)(xb + row * 128 + (kb ^ ((row & 7) << 4)));
            }
#pragma unroll
            for (int cc = 0; cc < 8; cc++) {
                int n = cc * 16 + lcol;
                b[cc] = *(const bf16x8*)(wb + n * 128 + (kb ^ ((n & 7) << 4)));
            }
#pragma unroll
            for (int r = 0; r < 2; r++)
#pragma unroll
                for (int cc = 0; cc < 8; cc++)
                    acc[r][cc] = __builtin_amdgcn_mfma_f32_16x16x32_bf16(a[r], b[cc], acc[r][cc], 0, 0, 0);
        }
        if (c < 3) {
#pragma unroll
            for (int i = 0; i < 4; i++) {
                int o = i * 4096 + t * 16;
                ushort8v b;
                b[0] = f2bf(xr[i][0].x); b[1] = f2bf(xr[i][0].y);
                b[2] = f2bf(xr[i][0].z); b[3] = f2bf(xr[i][0].w);
                b[4] = f2bf(xr[i][1].x); b[5] = f2bf(xr[i][1].y);
                b[6] = f2bf(xr[i][1].z); b[7] = f2bf(xr[i][1].w);
                *(ushort8v*)((char*)&Xs[buf ^ 1][0] + o) = b;
                *(uint4*)((char*)&Wl[buf ^ 1][0] + o) = wr[i];
            }
        }
        __syncthreads();
    }

    // epilogue: stage bf16 tile (reuses Xs: 2*16KB = exactly 128x128 bf16)
    ushort* Os = (ushort*)Xs;
#pragma unroll
    for (int r = 0; r < 2; r++)
#pragma unroll
        for (int cc = 0; cc < 8; cc++)
#pragma unroll
            for (int i = 0; i < 4; i++) {
                int rloc = rbase + r * 16 + (lane >> 4) * 4 + i;
                int col = cc * 16 + lcol;
                Os[rloc * 128 + col] = f2bf(acc[r][cc][i]);
            }
    __syncthreads();

    // fused el/er: 2 threads per row, row-rotated LDS reads
    {
        int row = t >> 1, half = t & 1;
        int grow = row0 + row;
        const ushort* orow = Os + row * 128 + half * 64;
        const float* alp = Al + half * 64;
        const float* arp = Ar + half * 64;
        float pl = 0.f, pr = 0.f;
        int rot = row & 7;
#pragma unroll
        for (int qq = 0; qq < 8; qq++) {
            int q = (qq + rot) & 7;
            ushort8v f8 = *(const ushort8v*)(orow + q * 8);
#pragma unroll
            for (int e = 0; e < 8; e++) {
                float fe = bf2f(f8[e]);
                pl += fe * alp[q * 8 + e];
                pr += fe * arp[q * 8 + e];
            }
        }
        pl += __shfl_down(pl, 1);
        pr += __shfl_down(pr, 1);
        if (!half && grow < NN) { el[grow] = pl; er[grow] = pr; }
    }

#pragma unroll
    for (int i = 0; i < 8; i++) {
        int u = i * 256 + t;
        int row = u >> 4;
        int grow = row0 + row;
        if (grow < NN)
            *(uint4*)(featb + (size_t)grow * 128 + (u & 15) * 8) =
                *(uint4*)((char*)Os + u * 16);
    }
}

// ---------------- fused softmax + aggregate (4-deep, exact balance) ----------------
__global__ __launch_bounds__(256) void aggregate(const int* __restrict__ off,
                                                 const int* __restrict__ deg,
                                                 const int* __restrict__ ssrc,
                                                 const float* __restrict__ el,
                                                 const float* __restrict__ er,
                                                 const ushort* __restrict__ featb,
                                                 ushort* __restrict__ hb,
                                                 const int* __restrict__ nsplit) {
    const int gid = blockIdx.x * 16 + (threadIdx.x >> 4);
    const int lc = threadIdx.x & 15;
    int n = nsplit[gid];
    const int nend = nsplit[gid + 1];
    const ushort* fb = featb + lc * 8;

    for (; n < nend; ++n) {
        const int e0 = off[n];
        const int dg = deg[n];
        const float erd = er[n];
        float acc[8];
#pragma unroll
        for (int q = 0; q < 8; q++) acc[q] = 0.f;
        float wsum = 0.f;

        int j = 0;
        for (; j + 4 <= dg; j += 4) {
            int s0 = ssrc[e0 + j + 0];
            int s1 = ssrc[e0 + j + 1];
            int s2 = ssrc[e0 + j + 2];
            int s3 = ssrc[e0 + j + 3];
            ushort8v f0 = *(const ushort8v*)(fb + (size_t)s0 * DHID);
            ushort8v f1 = *(const ushort8v*)(fb + (size_t)s1 * DHID);
            ushort8v f2 = *(const ushort8v*)(fb + (size_t)s2 * DHID);
            ushort8v f3 = *(const ushort8v*)(fb + (size_t)s3 * DHID);
            float x0 = el[s0] + erd, x1 = el[s1] + erd;
            float x2 = el[s2] + erd, x3 = el[s3] + erd;
            x0 = x0 > 0.f ? x0 : NEG_SLOPE * x0;
            x1 = x1 > 0.f ? x1 : NEG_SLOPE * x1;
            x2 = x2 > 0.f ? x2 : NEG_SLOPE * x2;
            x3 = x3 > 0.f ? x3 : NEG_SLOPE * x3;
            float w0 = __expf(x0), w1 = __expf(x1);
            float w2 = __expf(x2), w3 = __expf(x3);
            wsum += (w0 + w1) + (w2 + w3);
#pragma unroll
            for (int q = 0; q < 8; q++)
                acc[q] += (w0 * bf2f(f0[q]) + w1 * bf2f(f1[q])) +
                          (w2 * bf2f(f2[q]) + w3 * bf2f(f3[q]));
        }
        for (; j < dg; ++j) {
            int s0 = ssrc[e0 + j];
            ushort8v f0 = *(const ushort8v*)(fb + (size_t)s0 * DHID);
            float x0 = el[s0] + erd;
            x0 = x0 > 0.f ? x0 : NEG_SLOPE * x0;
            float w0 = __expf(x0);
            wsum += w0;
#pragma unroll
            for (int q = 0; q < 8; q++) acc[q] += w0 * bf2f(f0[q]);
        }

        float inv = (dg > 0) ? 1.0f / wsum : 0.f;
        ushort8v o8;
#pragma unroll
        for (int q = 0; q < 8; q++) o8[q] = f2bf(acc[q] * inv);
        *(ushort8v*)(hb + (size_t)n * DHID + lc * 8) = o8;
    }
}

// ---------------- GEMM2: out = bf16(h) @ bf16(fcW) + fcb, MFMA, direct store ----------------
__global__ __launch_bounds__(256) void gemm2(const ushort* __restrict__ hb,
                                             const ushort* __restrict__ fcWt,
                                             const float* __restrict__ fcb,
                                             float* __restrict__ out) {
    __shared__ ushort Hs[128 * 128];   // 32 KB
    __shared__ ushort Fs[64 * 128];    // 16 KB
    const int t = threadIdx.x;
    const int row0 = blockIdx.x * 128;

    {
#pragma unroll
        for (int i = 0; i < 8; i++) {
            int u = i * 256 + t;
            int row = u >> 4;
            int grow = row0 + row;
            uint4 v = make_uint4(0, 0, 0, 0);
            if (grow < NN) v = *(const uint4*)(hb + (size_t)grow * 128 + (u & 15) * 8);
            int byte_off = row * 256 + (((u & 15) * 16) ^ ((row & 7) << 4));
            *(uint4*)((char*)Hs + byte_off) = v;
        }
#pragma unroll
        for (int i = 0; i < 4; i++) {
            int u = i * 256 + t;
            int n = u >> 4;
            int byte_off = n * 256 + (((u & 15) * 16) ^ ((n & 7) << 4));
            *(uint4*)((char*)Fs + byte_off) = ((const uint4*)fcWt)[u];
        }
    }

    const int w = t >> 6, lane = t & 63;
    const int rbase = w * 32;
    const int lcol = lane & 15;
    const int kgrp = (lane >> 4) * 16;

    f32x4 acc[2][4];
#pragma unroll
    for (int c = 0; c < 4; c++) {
        float bias = fcb[c * 16 + lcol];
#pragma unroll
        for (int r = 0; r < 2; r++)
#pragma unroll
            for (int i = 0; i < 4; i++) acc[r][c][i] = bias;
    }
    __syncthreads();

#pragma unroll
    for (int k0 = 0; k0 < 4; k0++) {
        int kbyte = k0 * 64 + kgrp;
        bf16x8 a[2], b[4];
#pragma unroll
        for (int r = 0; r < 2; r++) {
            int row = rbase + r * 16 + lcol;
            a[r] = *(bf16x8*)((char*)Hs + row * 256 + (kbyte ^ ((row & 7) << 4)));
        }
#pragma unroll
        for (int c = 0; c < 4; c++) {
            int n = c * 16 + lcol;
            b[c] = *(bf16x8*)((char*)Fs + n * 256 + (kbyte ^ ((n & 7) << 4)));
        }
#pragma unroll
        for (int r = 0; r < 2; r++)
#pragma unroll
            for (int c = 0; c < 4; c++)
                acc[r][c] = __builtin_amdgcn_mfma_f32_16x16x32_bf16(a[r], b[c], acc[r][c], 0, 0, 0);
    }

    // direct store: per (r,c,i) lanes 0-15 write 64B contiguous
#pragma unroll
    for (int r = 0; r < 2; r++)
#pragma unroll
        for (int i = 0; i < 4; i++) {
            int row = rbase + r * 16 + (lane >> 4) * 4 + i;
            int grow = row0 + row;
            if (grow < NN) {
                float* op = out + (size_t)grow * 64 + lcol;
#pragma unroll
                for (int c = 0; c < 4; c++) op[c * 16] = acc[r][c][i];
            }
        }
}

// ---------------- launch ----------------
extern "C" void kernel_launch(void* const* d_in, const int* in_sizes, int n_in,
                              void* d_out, int out_size, void* d_ws, size_t ws_size,
                              hipStream_t stream) {
    const float* X      = (const float*)d_in[0];
    const float* W      = (const float*)d_in[1];
    const float* attn_l = (const float*)d_in[2];
    const float* attn_r = (const float*)d_in[3];
    const float* fcW    = (const float*)d_in[4];
    const float* fcb    = (const float*)d_in[5];
    const int*   src    = (const int*)d_in[6];
    const int*   dst    = (const int*)d_in[7];
    float* out = (float*)d_out;

    char* ws = (char*)d_ws;
    ushort* featb = (ushort*)ws;            ws += (size_t)NN * DHID * 2;
    ushort* hb    = (ushort*)ws;            ws += (size_t)NN * DHID * 2;
    ushort* Wt    = (ushort*)ws;            ws += (size_t)DHID * DIN * 2;
    ushort* fcWt  = (ushort*)ws;            ws += (size_t)NCLS * DHID * 2;
    float* el     = (float*)ws;             ws += (size_t)NN * 4;
    float* er     = (float*)ws;             ws += (size_t)NN * 4;
    int*   deg    = (int*)ws;               ws += (size_t)NN * 4;
    int*   off    = (int*)ws;               ws += (size_t)NN * 4;
    int*   ssrc   = (int*)ws;               ws += (size_t)NBUCK * ECAP * 4;
    unsigned* ebuf = (unsigned*)ws;         ws += (size_t)NBUCK * ECAP * 4;
    int*   gcur   = (int*)ws;               ws += (size_t)256 * 4;
    int*   bpre   = (int*)ws;               ws += (size_t)256 * 4;
    int*   nsplit = (int*)ws;               ws += (size_t)(NGRP + 1) * 4;

    hipMemsetAsync(gcur, 0, NBUCK * sizeof(int), stream);

    // CSR build (fixed-capacity bucketed counting sort)
    k_prep<<<64, 256, 0, stream>>>(W, fcW, Wt, fcWt);
    k_bin<<<NCHB, 256, 0, stream>>>(src, dst, gcur, ebuf);
    k_csr<<<NBUCK, 256, 0, stream>>>(ebuf, gcur, off, deg, ssrc);
    k_bpre<<<1, 256, 0, stream>>>(gcur, bpre);
    k_split<<<(NGRP + 256) / 256, 256, 0, stream>>>(off, bpre, nsplit);

    // dense pipeline (bf16 MFMA, el/er fused into gemm1 epilogue)
    gemm1<<<(NN + 127) / 128, 256, 0, stream>>>(X, Wt, attn_l, attn_r, featb, el, er);
    aggregate<<<NGRP / 16, 256, 0, stream>>>(off, deg, ssrc, el, er, featb, hb, nsplit);
    gemm2<<<(NN + 127) / 128, 256, 0, stream>>>(hb, fcWt, fcb, out);
}

// Round 11
// 170.598 us; speedup vs baseline: 1.2051x; 1.0130x over previous
//
#include <hip/hip_runtime.h>
#include <math.h>

#define NN 100000
#define NE 1600000
#define DIN 256
#define DHID 128
#define NCLS 64
#define NEG_SLOPE 0.2f

#define NBUCK 196          // ceil(NN / 512), bucket = dst >> 9
#define ECAP 10240         // fixed per-bucket ebuf capacity (mean 8192, +22 sigma)
#define CHUNK 4096
#define NCHB ((NE + CHUNK - 1) / CHUNK)   // 391
#define PREPB 32           // k_prep blocks inside fused_a

#define NGRP 32768         // edge-balanced 16-lane groups for aggregate
#define G1 ((NN + 127) / 128)             // 782 gemm1 blocks

typedef __bf16 bf16_t;
typedef bf16_t bf16x8 __attribute__((ext_vector_type(8)));
typedef float f32x4 __attribute__((ext_vector_type(4)));
typedef ushort ushort8v __attribute__((ext_vector_type(8)));
typedef ushort ushort4v __attribute__((ext_vector_type(4)));

__device__ __forceinline__ ushort f2bf(float f) {
    union { float f; unsigned u; } c; c.f = f;
    unsigned u = c.u;
    unsigned r = (u + 0x7FFFu + ((u >> 16) & 1u)) >> 16;
    return (ushort)r;
}
__device__ __forceinline__ float bf2f(ushort b) {
    return __uint_as_float(((unsigned)b) << 16);
}

// ================= fused_a: k_bin (CSR binning) ∪ k_prep (weight transpose) =================
union SmemA {
    struct {
        int hist[NBUCK];
        int scn[256];
        int loff[NBUCK];
        int cur[NBUCK];
        int gb[NBUCK];
        unsigned ord[CHUNK];
        ushort obk[CHUNK];
    } b;
};

__global__ __launch_bounds__(256) void fused_a(const int* __restrict__ src,
                                               const int* __restrict__ dst,
                                               int* __restrict__ gcur,
                                               unsigned* __restrict__ ebuf,
                                               const float* __restrict__ W,
                                               const float* __restrict__ fcW,
                                               ushort* __restrict__ Wt,
                                               ushort* __restrict__ fcWt) {
    __shared__ SmemA sm;
    const int t = threadIdx.x;

    if (blockIdx.x >= NCHB) {
        // ---- k_prep branch ----
        int t0 = (blockIdx.x - NCHB) * 256 + t;
        for (int i = t0; i < DHID * DIN; i += PREPB * 256) {   // Wt[n][k]
            int n = i >> 8, k = i & 255;
            Wt[i] = f2bf(W[k * DHID + n]);
        }
        for (int i = t0; i < NCLS * DHID; i += PREPB * 256) {  // fcWt[n][k]
            int n = i >> 7, k = i & 127;
            fcWt[i] = f2bf(fcW[k * NCLS + n]);
        }
        return;
    }

    // ---- k_bin branch ----
    const int base = blockIdx.x * CHUNK;
    int cnt = NE - base; if (cnt > CHUNK) cnt = CHUNK;

    for (int i = t; i < NBUCK; i += 256) sm.b.hist[i] = 0;
    __syncthreads();

    unsigned vals[16];
    int bks[16];
#pragma unroll
    for (int i = 0; i < 16; i++) {
        int idx = base + i * 256 + t;
        if (idx < NE) {
            int d = dst[idx], s = src[idx];
            int bb = d >> 9;
            bks[i] = bb;
            vals[i] = ((unsigned)(d & 511) << 17) | (unsigned)s;
            atomicAdd(&sm.b.hist[bb], 1);
        } else bks[i] = -1;
    }
    __syncthreads();

    int hv = (t < NBUCK) ? sm.b.hist[t] : 0;
    sm.b.scn[t] = hv;
    __syncthreads();
    for (int d = 1; d < 256; d <<= 1) {
        int a = (t >= d) ? sm.b.scn[t - d] : 0;
        __syncthreads();
        sm.b.scn[t] += a;
        __syncthreads();
    }
    if (t < NBUCK) { sm.b.loff[t] = sm.b.scn[t] - hv; sm.b.cur[t] = sm.b.scn[t] - hv; }
    __syncthreads();

#pragma unroll
    for (int i = 0; i < 16; i++) {
        if (bks[i] >= 0) {
            int slot = atomicAdd(&sm.b.cur[bks[i]], 1);
            sm.b.ord[slot] = vals[i];
            sm.b.obk[slot] = (ushort)bks[i];
        }
    }
    if (t < NBUCK && hv > 0) sm.b.gb[t] = t * ECAP + atomicAdd(&gcur[t], hv);
    __syncthreads();

    for (int s = t; s < cnt; s += 256) {
        int bb = sm.b.obk[s];
        ebuf[sm.b.gb[bb] + (s - sm.b.loff[bb])] = sm.b.ord[s];
    }
}

// ================= fused_b: gemm1 ∪ k_csr ∪ k_bpre =================
union SmemB {
    struct {
        ushort Xs[2][8192];   // 32 KB
        ushort Wl[2][8192];   // 32 KB
        float Al[DHID];
        float Ar[DHID];
    } g;
    struct {
        int sdeg[512];
        int pr[256];
        int lofs[512];
        int scnt[512];
    } c;
    int sh[256];
};

__global__ __launch_bounds__(256, 2) void fused_b(const float* __restrict__ X,
                                                  const ushort* __restrict__ Wt,
                                                  const float* __restrict__ attn_l,
                                                  const float* __restrict__ attn_r,
                                                  ushort* __restrict__ featb,
                                                  float* __restrict__ el,
                                                  float* __restrict__ er,
                                                  const unsigned* __restrict__ ebuf,
                                                  const int* __restrict__ gcur,
                                                  int* __restrict__ off_g,
                                                  int* __restrict__ deg_g,
                                                  int* __restrict__ ssrc,
                                                  int* __restrict__ bpre) {
    __shared__ SmemB sm;
    const int t = threadIdx.x;

    if (blockIdx.x >= G1 + NBUCK) {
        // ---- k_bpre branch (1 block) ----
        int v = (t < NBUCK) ? gcur[t] : 0;
        sm.sh[t] = v;
        __syncthreads();
        for (int d = 1; d < 256; d <<= 1) {
            int a = (t >= d) ? sm.sh[t - d] : 0;
            __syncthreads();
            sm.sh[t] += a;
            __syncthreads();
        }
        if (t < NBUCK) bpre[t] = sm.sh[t] - v;
        if (t == NBUCK - 1) bpre[NBUCK] = sm.sh[t];
        return;
    }

    if (blockIdx.x >= G1) {
        // ---- k_csr branch ----
        const int b = blockIdx.x - G1;
        const int node0 = b << 9;
        const int ebase = b * ECAP;
        const int ecnt = gcur[b];

        sm.c.sdeg[t] = 0; sm.c.sdeg[t + 256] = 0;
        __syncthreads();
        for (int s = t; s < ecnt; s += 256)
            atomicAdd(&sm.c.sdeg[ebuf[ebase + s] >> 17], 1);
        __syncthreads();

        int d0 = sm.c.sdeg[2 * t], d1 = sm.c.sdeg[2 * t + 1];
        sm.c.pr[t] = d0 + d1;
        __syncthreads();
        for (int d = 1; d < 256; d <<= 1) {
            int a = (t >= d) ? sm.c.pr[t - d] : 0;
            __syncthreads();
            sm.c.pr[t] += a;
            __syncthreads();
        }
        int ex = sm.c.pr[t] - d0 - d1;
        sm.c.lofs[2 * t] = ex;
        sm.c.lofs[2 * t + 1] = ex + d0;
        sm.c.scnt[2 * t] = 0; sm.c.scnt[2 * t + 1] = 0;
        int n0 = node0 + 2 * t, n1 = n0 + 1;
        if (n0 < NN) { off_g[n0] = ebase + ex;      deg_g[n0] = d0; }
        if (n1 < NN) { off_g[n1] = ebase + ex + d0; deg_g[n1] = d1; }
        __syncthreads();

        for (int s = t; s < ecnt; s += 256) {
            unsigned v = ebuf[ebase + s];
            int dl = v >> 17;
            int c = atomicAdd(&sm.c.scnt[dl], 1);
            ssrc[ebase + sm.c.lofs[dl] + c] = (int)(v & 0x1FFFFu);
        }
        return;
    }

    // ---- gemm1 branch ----
    const int row0 = blockIdx.x * 128;
    if (t < 128) { sm.g.Al[t] = attn_l[t]; sm.g.Ar[t] = attn_r[t]; }

    int srow[4], ske[4];
#pragma unroll
    for (int i = 0; i < 4; i++) {
        int o = i * 4096 + t * 16;
        int row = o >> 7;
        int bl = (o & 127) ^ ((row & 7) << 4);
        srow[i] = row;
        ske[i] = bl >> 1;
    }

    float4 xr[4][2];
    uint4  wr[4];

#pragma unroll
    for (int i = 0; i < 4; i++) {
        int grow = row0 + srow[i];
        if (grow < NN) {
            const float4* p = (const float4*)(X + (size_t)grow * DIN + ske[i]);
            xr[i][0] = p[0]; xr[i][1] = p[1];
        } else {
            xr[i][0] = make_float4(0.f, 0.f, 0.f, 0.f);
            xr[i][1] = make_float4(0.f, 0.f, 0.f, 0.f);
        }
        wr[i] = *(const uint4*)(Wt + (size_t)srow[i] * DIN + ske[i]);
    }
#pragma unroll
    for (int i = 0; i < 4; i++) {
        int o = i * 4096 + t * 16;
        ushort8v b;
        b[0] = f2bf(xr[i][0].x); b[1] = f2bf(xr[i][0].y);
        b[2] = f2bf(xr[i][0].z); b[3] = f2bf(xr[i][0].w);
        b[4] = f2bf(xr[i][1].x); b[5] = f2bf(xr[i][1].y);
        b[6] = f2bf(xr[i][1].z); b[7] = f2bf(xr[i][1].w);
        *(ushort8v*)((char*)&sm.g.Xs[0][0] + o) = b;
        *(uint4*)((char*)&sm.g.Wl[0][0] + o) = wr[i];
    }
    __syncthreads();

    const int w = t >> 6, lane = t & 63;
    const int rbase = w * 32;
    const int lcol = lane & 15;
    const int kgrp = (lane >> 4) * 16;

    f32x4 acc[2][8];
#pragma unroll
    for (int r = 0; r < 2; r++)
#pragma unroll
        for (int c = 0; c < 8; c++) acc[r][c] = (f32x4){0.f, 0.f, 0.f, 0.f};

    for (int c = 0; c < 4; c++) {
        const int buf = c & 1;
        if (c < 3) {
            int k0g = (c + 1) * 64;
#pragma unroll
            for (int i = 0; i < 4; i++) {
                int grow = row0 + srow[i];
                if (grow < NN) {
                    const float4* p = (const float4*)(X + (size_t)grow * DIN + k0g + ske[i]);
                    xr[i][0] = p[0]; xr[i][1] = p[1];
                } else {
                    xr[i][0] = make_float4(0.f, 0.f, 0.f, 0.f);
                    xr[i][1] = make_float4(0.f, 0.f, 0.f, 0.f);
                }
                wr[i] = *(const uint4*)(Wt + (size_t)srow[i] * DIN + k0g + ske[i]);
            }
        }
        const char* xb = (const char*)&sm.g.Xs[buf][0];
        const char* wb = (const char*)&sm.g.Wl[buf][0];
#pragma unroll
        for (int k0 = 0; k0 < 2; k0++) {
            int kb = k0 * 64 + kgrp;
            bf16x8 a[2], b[8];
#pragma unroll
            for (int r = 0; r < 2; r++) {
                int row = rbase + r * 16 + lcol;
                a[r] = *(const bf16x8*)(xb + row * 128 + (kb ^ ((row & 7) << 4)));
            }
#pragma unroll
            for (int cc = 0; cc < 8; cc++) {
                int n = cc * 16 + lcol;
                b[cc] = *(const bf16x8*)(wb + n * 128 + (kb ^ ((n & 7) << 4)));
            }
#pragma unroll
            for (int r = 0; r < 2; r++)
#pragma unroll
                for (int cc = 0; cc < 8; cc++)
                    acc[r][cc] = __builtin_amdgcn_mfma_f32_16x16x32_bf16(a[r], b[cc], acc[r][cc], 0, 0, 0);
        }
        if (c < 3) {
#pragma unroll
            for (int i = 0; i < 4; i++) {
                int o = i * 4096 + t * 16;
                ushort8v b;
                b[0] = f2bf(xr[i][0].x); b[1] = f2bf(xr[i][0].y);
                b[2] = f2bf(xr[i][0].z); b[3] = f2bf(xr[i][0].w);
                b[4] = f2bf(xr[i][1].x); b[5] = f2bf(xr[i][1].y);
                b[6] = f2bf(xr[i][1].z); b[7] = f2bf(xr[i][1].w);
                *(ushort8v*)((char*)&sm.g.Xs[buf ^ 1][0] + o) = b;
                *(uint4*)((char*)&sm.g.Wl[buf ^ 1][0] + o) = wr[i];
            }
        }
        __syncthreads();
    }

    // epilogue: stage bf16 tile (reuses Xs: 2*16KB = exactly 128x128 bf16)
    ushort* Os = (ushort*)sm.g.Xs;
#pragma unroll
    for (int r = 0; r < 2; r++)
#pragma unroll
        for (int cc = 0; cc < 8; cc++)
#pragma unroll
            for (int i = 0; i < 4; i++) {
                int rloc = rbase + r * 16 + (lane >> 4) * 4 + i;
                int col = cc * 16 + lcol;
                Os[rloc * 128 + col] = f2bf(acc[r][cc][i]);
            }
    __syncthreads();

    // fused el/er: 2 threads per row, row-rotated LDS reads
    {
        int row = t >> 1, half = t & 1;
        int grow = row0 + row;
        const ushort* orow = Os + row * 128 + half * 64;
        const float* alp = sm.g.Al + half * 64;
        const float* arp = sm.g.Ar + half * 64;
        float pl = 0.f, pr = 0.f;
        int rot = row & 7;
#pragma unroll
        for (int qq = 0; qq < 8; qq++) {
            int q = (qq + rot) & 7;
            ushort8v f8 = *(const ushort8v*)(orow + q * 8);
#pragma unroll
            for (int e = 0; e < 8; e++) {
                float fe = bf2f(f8[e]);
                pl += fe * alp[q * 8 + e];
                pr += fe * arp[q * 8 + e];
            }
        }
        pl += __shfl_down(pl, 1);
        pr += __shfl_down(pr, 1);
        if (!half && grow < NN) { el[grow] = pl; er[grow] = pr; }
    }

#pragma unroll
    for (int i = 0; i < 8; i++) {
        int u = i * 256 + t;
        int row = u >> 4;
        int grow = row0 + row;
        if (grow < NN)
            *(uint4*)(featb + (size_t)grow * 128 + (u & 15) * 8) =
                *(uint4*)((char*)Os + u * 16);
    }
}

// ---------------- edge-balanced group partition (binary search, exact) ----------------
__global__ __launch_bounds__(256) void k_split(const int* __restrict__ off,
                                               const int* __restrict__ bpre,
                                               int* __restrict__ nsplit) {
    int g = blockIdx.x * 256 + threadIdx.x;
    if (g > NGRP) return;
    if (g == NGRP) { nsplit[NGRP] = NN; return; }
    long total = bpre[NBUCK];
    long target = (long)g * total / NGRP;
    int lo = 0, hi = NN;          // smallest n with real(n) >= target
    while (lo < hi) {
        int mid = (lo + hi) >> 1;
        int b = mid >> 9;
        long real = (long)off[mid] - (long)b * ECAP + bpre[b];
        if (real < target) lo = mid + 1; else hi = mid;
    }
    nsplit[g] = lo;
}

// ---------------- fused softmax + aggregate, column-split by XCD parity ----------------
// Each node handled by TWO 16-lane groups: half = blockIdx&1 selects cols
// [half*64, half*64+64). Lane owns 4 cols (8B load -> 1 cache line per edge
// per group). 8 edges in flight. wsum computed redundantly per half
// (identical fp sequence -> consistent normalization).
__global__ __launch_bounds__(256) void aggregate(const int* __restrict__ off,
                                                 const int* __restrict__ deg,
                                                 const int* __restrict__ ssrc,
                                                 const float* __restrict__ el,
                                                 const float* __restrict__ er,
                                                 const ushort* __restrict__ featb,
                                                 ushort* __restrict__ hb,
                                                 const int* __restrict__ nsplit) {
    const int half = blockIdx.x & 1;
    const int gid = (blockIdx.x >> 1) * 16 + (threadIdx.x >> 4);
    const int lc = threadIdx.x & 15;
    int n = nsplit[gid];
    const int nend = nsplit[gid + 1];
    const ushort* fb = featb + half * 64 + lc * 4;
    ushort* hbh = hb + half * 64 + lc * 4;

    for (; n < nend; ++n) {
        const int e0 = off[n];
        const int dg = deg[n];
        const float erd = er[n];
        float acc0 = 0.f, acc1 = 0.f, acc2 = 0.f, acc3 = 0.f;
        float wsum = 0.f;

        int j = 0;
        for (; j + 8 <= dg; j += 8) {
            int sv[8];
            ushort4v fv[8];
            float wv[8];
#pragma unroll
            for (int u = 0; u < 8; u++) sv[u] = ssrc[e0 + j + u];
#pragma unroll
            for (int u = 0; u < 8; u++)
                fv[u] = *(const ushort4v*)(fb + (size_t)sv[u] * DHID);
#pragma unroll
            for (int u = 0; u < 8; u++) {
                float x = el[sv[u]] + erd;
                x = x > 0.f ? x : NEG_SLOPE * x;
                wv[u] = __expf(x);
                wsum += wv[u];
            }
#pragma unroll
            for (int u = 0; u < 8; u++) {
                acc0 += wv[u] * bf2f(fv[u][0]);
                acc1 += wv[u] * bf2f(fv[u][1]);
                acc2 += wv[u] * bf2f(fv[u][2]);
                acc3 += wv[u] * bf2f(fv[u][3]);
            }
        }
        for (; j < dg; ++j) {
            int s0 = ssrc[e0 + j];
            ushort4v f0 = *(const ushort4v*)(fb + (size_t)s0 * DHID);
            float x0 = el[s0] + erd;
            x0 = x0 > 0.f ? x0 : NEG_SLOPE * x0;
            float w0 = __expf(x0);
            wsum += w0;
            acc0 += w0 * bf2f(f0[0]);
            acc1 += w0 * bf2f(f0[1]);
            acc2 += w0 * bf2f(f0[2]);
            acc3 += w0 * bf2f(f0[3]);
        }

        float inv = (dg > 0) ? 1.0f / wsum : 0.f;
        ushort4v o4;
        o4[0] = f2bf(acc0 * inv);
        o4[1] = f2bf(acc1 * inv);
        o4[2] = f2bf(acc2 * inv);
        o4[3] = f2bf(acc3 * inv);
        *(ushort4v*)(hbh + (size_t)n * DHID) = o4;
    }
}

// ---------------- GEMM2: out = bf16(h) @ bf16(fcW) + fcb, MFMA, direct store ----------------
__global__ __launch_bounds__(256) void gemm2(const ushort* __restrict__ hb,
                                             const ushort* __restrict__ fcWt,
                                             const float* __restrict__ fcb,
                                             float* __restrict__ out) {
    __shared__ ushort Hs[128 * 128];   // 32 KB
    __shared__ ushort Fs[64 * 128];    // 16 KB
    const int t = threadIdx.x;
    const int row0 = blockIdx.x * 128;

    {
#pragma unroll
        for (int i = 0; i < 8; i++) {
            int u = i * 256 + t;
            int row = u >> 4;
            int grow = row0 + row;
            uint4 v = make_uint4(0, 0, 0, 0);
            if (grow < NN) v = *(const uint4*)(hb + (size_t)grow * 128 + (u & 15) * 8);
            int byte_off = row * 256 + (((u & 15) * 16) ^ ((row & 7) << 4));
            *(uint4*)((char*)Hs + byte_off) = v;
        }
#pragma unroll
        for (int i = 0; i < 4; i++) {
            int u = i * 256 + t;
            int n = u >> 4;
            int byte_off = n * 256 + (((u & 15) * 16) ^ ((n & 7) << 4));
            *(uint4*)((char*)Fs + byte_off) = ((const uint4*)fcWt)[u];
        }
    }

    const int w = t >> 6, lane = t & 63;
    const int rbase = w * 32;
    const int lcol = lane & 15;
    const int kgrp = (lane >> 4) * 16;

    f32x4 acc[2][4];
#pragma unroll
    for (int c = 0; c < 4; c++) {
        float bias = fcb[c * 16 + lcol];
#pragma unroll
        for (int r = 0; r < 2; r++)
#pragma unroll
            for (int i = 0; i < 4; i++) acc[r][c][i] = bias;
    }
    __syncthreads();

#pragma unroll
    for (int k0 = 0; k0 < 4; k0++) {
        int kbyte = k0 * 64 + kgrp;
        bf16x8 a[2], b[4];
#pragma unroll
        for (int r = 0; r < 2; r++) {
            int row = rbase + r * 16 + lcol;
            a[r] = *(bf16x8*)((char*)Hs + row * 256 + (kbyte ^ ((row & 7) << 4)));
        }
#pragma unroll
        for (int c = 0; c < 4; c++) {
            int n = c * 16 + lcol;
            b[c] = *(bf16x8*)((char*)Fs + n * 256 + (kbyte ^ ((n & 7) << 4)));
        }
#pragma unroll
        for (int r = 0; r < 2; r++)
#pragma unroll
            for (int c = 0; c < 4; c++)
                acc[r][c] = __builtin_amdgcn_mfma_f32_16x16x32_bf16(a[r], b[c], acc[r][c], 0, 0, 0);
    }

    // direct store: per (r,c,i) lanes 0-15 write 64B contiguous
#pragma unroll
    for (int r = 0; r < 2; r++)
#pragma unroll
        for (int i = 0; i < 4; i++) {
            int row = rbase + r * 16 + (lane >> 4) * 4 + i;
            int grow = row0 + row;
            if (grow < NN) {
                float* op = out + (size_t)grow * 64 + lcol;
#pragma unroll
                for (int c = 0; c < 4; c++) op[c * 16] = acc[r][c][i];
            }
        }
}

// ---------------- launch ----------------
extern "C" void kernel_launch(void* const* d_in, const int* in_sizes, int n_in,
                              void* d_out, int out_size, void* d_ws, size_t ws_size,
                              hipStream_t stream) {
    const float* X      = (const float*)d_in[0];
    const float* W      = (const float*)d_in[1];
    const float* attn_l = (const float*)d_in[2];
    const float* attn_r = (const float*)d_in[3];
    const float* fcW    = (const float*)d_in[4];
    const float* fcb    = (const float*)d_in[5];
    const int*   src    = (const int*)d_in[6];
    const int*   dst    = (const int*)d_in[7];
    float* out = (float*)d_out;

    char* ws = (char*)d_ws;
    ushort* featb = (ushort*)ws;            ws += (size_t)NN * DHID * 2;
    ushort* hb    = (ushort*)ws;            ws += (size_t)NN * DHID * 2;
    ushort* Wt    = (ushort*)ws;            ws += (size_t)DHID * DIN * 2;
    ushort* fcWt  = (ushort*)ws;            ws += (size_t)NCLS * DHID * 2;
    float* el     = (float*)ws;             ws += (size_t)NN * 4;
    float* er     = (float*)ws;             ws += (size_t)NN * 4;
    int*   deg    = (int*)ws;               ws += (size_t)NN * 4;
    int*   off    = (int*)ws;               ws += (size_t)NN * 4;
    int*   ssrc   = (int*)ws;               ws += (size_t)NBUCK * ECAP * 4;
    unsigned* ebuf = (unsigned*)ws;         ws += (size_t)NBUCK * ECAP * 4;
    int*   gcur   = (int*)ws;               ws += (size_t)256 * 4;
    int*   bpre   = (int*)ws;               ws += (size_t)256 * 4;
    int*   nsplit = (int*)ws;               ws += (size_t)(NGRP + 1) * 4;

    hipMemsetAsync(gcur, 0, NBUCK * sizeof(int), stream);

    // fused_a: CSR binning + weight prep (independent)
    fused_a<<<NCHB + PREPB, 256, 0, stream>>>(src, dst, gcur, ebuf, W, fcW, Wt, fcWt);
    // fused_b: gemm1 (+el/er) + per-bucket CSR finalize + bucket prefix
    fused_b<<<G1 + NBUCK + 1, 256, 0, stream>>>(X, Wt, attn_l, attn_r, featb, el, er,
                                                ebuf, gcur, off, deg, ssrc, bpre);
    k_split<<<(NGRP + 256) / 256, 256, 0, stream>>>(off, bpre, nsplit);
    aggregate<<<(NGRP / 16) * 2, 256, 0, stream>>>(off, deg, ssrc, el, er, featb, hb, nsplit);
    gemm2<<<(NN + 127) / 128, 256, 0, stream>>>(hb, fcWt, fcb, out);
}

// Round 12
// 160.382 us; speedup vs baseline: 1.2818x; 1.0637x over previous
//
#include <hip/hip_runtime.h>
#include <math.h>

#define NN 100000
#define NE 1600000
#define DIN 256
#define DHID 128
#define NCLS 64
#define NEG_SLOPE 0.2f

#define NBUCK 196          // ceil(NN / 512), bucket = dst >> 9
#define ECAP 10240         // fixed per-bucket ebuf capacity (mean 8192, +22 sigma)
#define CHUNK 4096
#define NCHB ((NE + CHUNK - 1) / CHUNK)   // 391
#define PREPB 16

#define NGRP 16384         // edge-balanced 16-lane groups for aggregate
#define G1 ((NN + 127) / 128)             // 782 gemm1 blocks

typedef __bf16 bf16_t;
typedef bf16_t bf16x8 __attribute__((ext_vector_type(8)));
typedef float f32x4 __attribute__((ext_vector_type(4)));
typedef ushort ushort8v __attribute__((ext_vector_type(8)));

__device__ __forceinline__ ushort f2bf(float f) {
    union { float f; unsigned u; } c; c.f = f;
    unsigned u = c.u;
    unsigned r = (u + 0x7FFFu + ((u >> 16) & 1u)) >> 16;
    return (ushort)r;
}
__device__ __forceinline__ float bf2f(ushort b) {
    return __uint_as_float(((unsigned)b) << 16);
}

// ================= kA: weight prep + gcur zero =================
__global__ __launch_bounds__(256) void k_prep(const float* __restrict__ W,
                                              const float* __restrict__ fcW,
                                              ushort* __restrict__ Wt,
                                              ushort* __restrict__ fcWt,
                                              int* __restrict__ gcur) {
    int t = blockIdx.x * 256 + threadIdx.x;
    if (blockIdx.x == 0) gcur[threadIdx.x] = 0;
    for (int i = t; i < DHID * DIN; i += PREPB * 256) {   // Wt[n][k]
        int n = i >> 8, k = i & 255;
        Wt[i] = f2bf(W[k * DHID + n]);
    }
    for (int i = t; i < NCLS * DHID; i += PREPB * 256) {  // fcWt[n][k]
        int n = i >> 7, k = i & 127;
        fcWt[i] = f2bf(fcW[k * NCLS + n]);
    }
}

// ================= kB: k_bin ∪ gemm1 (independent work, co-resident) =================
union SmemB {
    struct {                      // k_bin branch (~30 KB)
        int hist[NBUCK];
        int scn[256];
        int loff[NBUCK];
        int cur[NBUCK];
        int gb[NBUCK];
        unsigned ord[CHUNK];
        ushort obk[CHUNK];
    } b;
    struct {                      // gemm1 branch (~65 KB)
        ushort Xs[2][8192];
        ushort Wl[2][8192];
        float Al[DHID];
        float Ar[DHID];
    } g;
};

__global__ __launch_bounds__(256, 2) void fused_bin_gemm1(
        const int* __restrict__ src, const int* __restrict__ dst,
        int* __restrict__ gcur, unsigned* __restrict__ ebuf,
        const float* __restrict__ X, const ushort* __restrict__ Wt,
        const float* __restrict__ attn_l, const float* __restrict__ attn_r,
        ushort* __restrict__ featb, float* __restrict__ el, float* __restrict__ er) {
    __shared__ SmemB sm;
    const int t = threadIdx.x;

    if (blockIdx.x < NCHB) {
        // ---- k_bin branch ----
        const int base = blockIdx.x * CHUNK;
        int cnt = NE - base; if (cnt > CHUNK) cnt = CHUNK;

        for (int i = t; i < NBUCK; i += 256) sm.b.hist[i] = 0;
        __syncthreads();

        unsigned vals[16];
        int bks[16];
#pragma unroll
        for (int i = 0; i < 16; i++) {
            int idx = base + i * 256 + t;
            if (idx < NE) {
                int d = dst[idx], s = src[idx];
                int bb = d >> 9;
                bks[i] = bb;
                vals[i] = ((unsigned)(d & 511) << 17) | (unsigned)s;
                atomicAdd(&sm.b.hist[bb], 1);
            } else bks[i] = -1;
        }
        __syncthreads();

        int hv = (t < NBUCK) ? sm.b.hist[t] : 0;
        sm.b.scn[t] = hv;
        __syncthreads();
        for (int d = 1; d < 256; d <<= 1) {
            int a = (t >= d) ? sm.b.scn[t - d] : 0;
            __syncthreads();
            sm.b.scn[t] += a;
            __syncthreads();
        }
        if (t < NBUCK) { sm.b.loff[t] = sm.b.scn[t] - hv; sm.b.cur[t] = sm.b.scn[t] - hv; }
        __syncthreads();

#pragma unroll
        for (int i = 0; i < 16; i++) {
            if (bks[i] >= 0) {
                int slot = atomicAdd(&sm.b.cur[bks[i]], 1);
                sm.b.ord[slot] = vals[i];
                sm.b.obk[slot] = (ushort)bks[i];
            }
        }
        if (t < NBUCK && hv > 0) sm.b.gb[t] = t * ECAP + atomicAdd(&gcur[t], hv);
        __syncthreads();

        for (int s = t; s < cnt; s += 256) {
            int bb = sm.b.obk[s];
            ebuf[sm.b.gb[bb] + (s - sm.b.loff[bb])] = sm.b.ord[s];
        }
        return;
    }

    // ---- gemm1 branch ----
    const int row0 = (blockIdx.x - NCHB) * 128;
    if (t < 128) { sm.g.Al[t] = attn_l[t]; sm.g.Ar[t] = attn_r[t]; }

    int srow[4], ske[4];
#pragma unroll
    for (int i = 0; i < 4; i++) {
        int o = i * 4096 + t * 16;
        int row = o >> 7;
        int bl = (o & 127) ^ ((row & 7) << 4);
        srow[i] = row;
        ske[i] = bl >> 1;
    }

    float4 xr[4][2];
    uint4  wr[4];

#pragma unroll
    for (int i = 0; i < 4; i++) {
        int grow = row0 + srow[i];
        if (grow < NN) {
            const float4* p = (const float4*)(X + (size_t)grow * DIN + ske[i]);
            xr[i][0] = p[0]; xr[i][1] = p[1];
        } else {
            xr[i][0] = make_float4(0.f, 0.f, 0.f, 0.f);
            xr[i][1] = make_float4(0.f, 0.f, 0.f, 0.f);
        }
        wr[i] = *(const uint4*)(Wt + (size_t)srow[i] * DIN + ske[i]);
    }
#pragma unroll
    for (int i = 0; i < 4; i++) {
        int o = i * 4096 + t * 16;
        ushort8v b;
        b[0] = f2bf(xr[i][0].x); b[1] = f2bf(xr[i][0].y);
        b[2] = f2bf(xr[i][0].z); b[3] = f2bf(xr[i][0].w);
        b[4] = f2bf(xr[i][1].x); b[5] = f2bf(xr[i][1].y);
        b[6] = f2bf(xr[i][1].z); b[7] = f2bf(xr[i][1].w);
        *(ushort8v*)((char*)&sm.g.Xs[0][0] + o) = b;
        *(uint4*)((char*)&sm.g.Wl[0][0] + o) = wr[i];
    }
    __syncthreads();

    const int w = t >> 6, lane = t & 63;
    const int rbase = w * 32;
    const int lcol = lane & 15;
    const int kgrp = (lane >> 4) * 16;

    f32x4 acc[2][8];
#pragma unroll
    for (int r = 0; r < 2; r++)
#pragma unroll
        for (int c = 0; c < 8; c++) acc[r][c] = (f32x4){0.f, 0.f, 0.f, 0.f};

    for (int c = 0; c < 4; c++) {
        const int buf = c & 1;
        if (c < 3) {
            int k0g = (c + 1) * 64;
#pragma unroll
            for (int i = 0; i < 4; i++) {
                int grow = row0 + srow[i];
                if (grow < NN) {
                    const float4* p = (const float4*)(X + (size_t)grow * DIN + k0g + ske[i]);
                    xr[i][0] = p[0]; xr[i][1] = p[1];
                } else {
                    xr[i][0] = make_float4(0.f, 0.f, 0.f, 0.f);
                    xr[i][1] = make_float4(0.f, 0.f, 0.f, 0.f);
                }
                wr[i] = *(const uint4*)(Wt + (size_t)srow[i] * DIN + k0g + ske[i]);
            }
        }
        const char* xb = (const char*)&sm.g.Xs[buf][0];
        const char* wb = (const char*)&sm.g.Wl[buf][0];
#pragma unroll
        for (int k0 = 0; k0 < 2; k0++) {
            int kb = k0 * 64 + kgrp;
            bf16x8 a[2], b[8];
#pragma unroll
            for (int r = 0; r < 2; r++) {
                int row = rbase + r * 16 + lcol;
                a[r] = *(const bf16x8*)(xb + row * 128 + (kb ^ ((row & 7) << 4)));
            }
#pragma unroll
            for (int cc = 0; cc < 8; cc++) {
                int n = cc * 16 + lcol;
                b[cc] = *(const bf16x8*)(wb + n * 128 + (kb ^ ((n & 7) << 4)));
            }
#pragma unroll
            for (int r = 0; r < 2; r++)
#pragma unroll
                for (int cc = 0; cc < 8; cc++)
                    acc[r][cc] = __builtin_amdgcn_mfma_f32_16x16x32_bf16(a[r], b[cc], acc[r][cc], 0, 0, 0);
        }
        if (c < 3) {
#pragma unroll
            for (int i = 0; i < 4; i++) {
                int o = i * 4096 + t * 16;
                ushort8v b;
                b[0] = f2bf(xr[i][0].x); b[1] = f2bf(xr[i][0].y);
                b[2] = f2bf(xr[i][0].z); b[3] = f2bf(xr[i][0].w);
                b[4] = f2bf(xr[i][1].x); b[5] = f2bf(xr[i][1].y);
                b[6] = f2bf(xr[i][1].z); b[7] = f2bf(xr[i][1].w);
                *(ushort8v*)((char*)&sm.g.Xs[buf ^ 1][0] + o) = b;
                *(uint4*)((char*)&sm.g.Wl[buf ^ 1][0] + o) = wr[i];
            }
        }
        __syncthreads();
    }

    ushort* Os = (ushort*)sm.g.Xs;
#pragma unroll
    for (int r = 0; r < 2; r++)
#pragma unroll
        for (int cc = 0; cc < 8; cc++)
#pragma unroll
            for (int i = 0; i < 4; i++) {
                int rloc = rbase + r * 16 + (lane >> 4) * 4 + i;
                int col = cc * 16 + lcol;
                Os[rloc * 128 + col] = f2bf(acc[r][cc][i]);
            }
    __syncthreads();

    // fused el/er: 2 threads per row, row-rotated LDS reads
    {
        int row = t >> 1, half = t & 1;
        int grow = row0 + row;
        const ushort* orow = Os + row * 128 + half * 64;
        const float* alp = sm.g.Al + half * 64;
        const float* arp = sm.g.Ar + half * 64;
        float pl = 0.f, pr = 0.f;
        int rot = row & 7;
#pragma unroll
        for (int qq = 0; qq < 8; qq++) {
            int q = (qq + rot) & 7;
            ushort8v f8 = *(const ushort8v*)(orow + q * 8);
#pragma unroll
            for (int e = 0; e < 8; e++) {
                float fe = bf2f(f8[e]);
                pl += fe * alp[q * 8 + e];
                pr += fe * arp[q * 8 + e];
            }
        }
        pl += __shfl_down(pl, 1);
        pr += __shfl_down(pr, 1);
        if (!half && grow < NN) { el[grow] = pl; er[grow] = pr; }
    }

#pragma unroll
    for (int i = 0; i < 8; i++) {
        int u = i * 256 + t;
        int row = u >> 4;
        int grow = row0 + row;
        if (grow < NN)
            *(uint4*)(featb + (size_t)grow * 128 + (u & 15) * 8) =
                *(uint4*)((char*)Os + u * 16);
    }
}

// ================= kC: k_csr ∪ k_bpre =================
union SmemC {
    struct {
        int sdeg[512];
        int pr[256];
        int lofs[512];
        int scnt[512];
    } c;
    int sh[256];
};

__global__ __launch_bounds__(256) void fused_csr(const unsigned* __restrict__ ebuf,
                                                 const int* __restrict__ gcur,
                                                 int* __restrict__ off_g,
                                                 int* __restrict__ deg_g,
                                                 int* __restrict__ ssrc,
                                                 int* __restrict__ bpre) {
    __shared__ SmemC sm;
    const int t = threadIdx.x;

    if (blockIdx.x == NBUCK) {
        // ---- bpre branch ----
        int v = (t < NBUCK) ? gcur[t] : 0;
        sm.sh[t] = v;
        __syncthreads();
        for (int d = 1; d < 256; d <<= 1) {
            int a = (t >= d) ? sm.sh[t - d] : 0;
            __syncthreads();
            sm.sh[t] += a;
            __syncthreads();
        }
        if (t < NBUCK) bpre[t] = sm.sh[t] - v;
        if (t == NBUCK - 1) bpre[NBUCK] = sm.sh[t];
        return;
    }

    const int b = blockIdx.x;
    const int node0 = b << 9;
    const int ebase = b * ECAP;
    const int ecnt = gcur[b];

    sm.c.sdeg[t] = 0; sm.c.sdeg[t + 256] = 0;
    __syncthreads();
    for (int s = t; s < ecnt; s += 256)
        atomicAdd(&sm.c.sdeg[ebuf[ebase + s] >> 17], 1);
    __syncthreads();

    int d0 = sm.c.sdeg[2 * t], d1 = sm.c.sdeg[2 * t + 1];
    sm.c.pr[t] = d0 + d1;
    __syncthreads();
    for (int d = 1; d < 256; d <<= 1) {
        int a = (t >= d) ? sm.c.pr[t - d] : 0;
        __syncthreads();
        sm.c.pr[t] += a;
        __syncthreads();
    }
    int ex = sm.c.pr[t] - d0 - d1;
    sm.c.lofs[2 * t] = ex;
    sm.c.lofs[2 * t + 1] = ex + d0;
    sm.c.scnt[2 * t] = 0; sm.c.scnt[2 * t + 1] = 0;
    int n0 = node0 + 2 * t, n1 = n0 + 1;
    if (n0 < NN) { off_g[n0] = ebase + ex;      deg_g[n0] = d0; }
    if (n1 < NN) { off_g[n1] = ebase + ex + d0; deg_g[n1] = d1; }
    __syncthreads();

    for (int s = t; s < ecnt; s += 256) {
        unsigned v = ebuf[ebase + s];
        int dl = v >> 17;
        int c = atomicAdd(&sm.c.scnt[dl], 1);
        ssrc[ebase + sm.c.lofs[dl] + c] = (int)(v & 0x1FFFFu);
    }
}

// ================= kE: aggregate (full-row, 4-deep, self-search) =================
__device__ __forceinline__ int find_node(const int* __restrict__ off,
                                         const int* __restrict__ bpre,
                                         long target) {
    int lo = 0, hi = NN;
    while (lo < hi) {
        int mid = (lo + hi) >> 1;
        int b = mid >> 9;
        long real = (long)off[mid] - (long)b * ECAP + bpre[b];
        if (real < target) lo = mid + 1; else hi = mid;
    }
    return lo;
}

__global__ __launch_bounds__(256) void aggregate(const int* __restrict__ off,
                                                 const int* __restrict__ deg,
                                                 const int* __restrict__ ssrc,
                                                 const float* __restrict__ el,
                                                 const float* __restrict__ er,
                                                 const ushort* __restrict__ featb,
                                                 ushort* __restrict__ hb,
                                                 const int* __restrict__ bpre) {
    const int gid = blockIdx.x * 16 + (threadIdx.x >> 4);
    const int lc = threadIdx.x & 15;
    const long total = bpre[NBUCK];
    int n = find_node(off, bpre, (long)gid * total / NGRP);
    const int nend = find_node(off, bpre, (long)(gid + 1) * total / NGRP);
    const ushort* fb = featb + lc * 8;

    for (; n < nend; ++n) {
        const int e0 = off[n];
        const int dg = deg[n];
        const float erd = er[n];
        float acc[8];
#pragma unroll
        for (int q = 0; q < 8; q++) acc[q] = 0.f;
        float wsum = 0.f;

        int j = 0;
        for (; j + 4 <= dg; j += 4) {
            int s0 = ssrc[e0 + j + 0];
            int s1 = ssrc[e0 + j + 1];
            int s2 = ssrc[e0 + j + 2];
            int s3 = ssrc[e0 + j + 3];
            ushort8v f0 = *(const ushort8v*)(fb + (size_t)s0 * DHID);
            ushort8v f1 = *(const ushort8v*)(fb + (size_t)s1 * DHID);
            ushort8v f2 = *(const ushort8v*)(fb + (size_t)s2 * DHID);
            ushort8v f3 = *(const ushort8v*)(fb + (size_t)s3 * DHID);
            float x0 = el[s0] + erd, x1 = el[s1] + erd;
            float x2 = el[s2] + erd, x3 = el[s3] + erd;
            x0 = x0 > 0.f ? x0 : NEG_SLOPE * x0;
            x1 = x1 > 0.f ? x1 : NEG_SLOPE * x1;
            x2 = x2 > 0.f ? x2 : NEG_SLOPE * x2;
            x3 = x3 > 0.f ? x3 : NEG_SLOPE * x3;
            float w0 = __expf(x0), w1 = __expf(x1);
            float w2 = __expf(x2), w3 = __expf(x3);
            wsum += (w0 + w1) + (w2 + w3);
#pragma unroll
            for (int q = 0; q < 8; q++)
                acc[q] += (w0 * bf2f(f0[q]) + w1 * bf2f(f1[q])) +
                          (w2 * bf2f(f2[q]) + w3 * bf2f(f3[q]));
        }
        for (; j < dg; ++j) {
            int s0 = ssrc[e0 + j];
            ushort8v f0 = *(const ushort8v*)(fb + (size_t)s0 * DHID);
            float x0 = el[s0] + erd;
            x0 = x0 > 0.f ? x0 : NEG_SLOPE * x0;
            float w0 = __expf(x0);
            wsum += w0;
#pragma unroll
            for (int q = 0; q < 8; q++) acc[q] += w0 * bf2f(f0[q]);
        }

        float inv = (dg > 0) ? 1.0f / wsum : 0.f;
        ushort8v o8;
#pragma unroll
        for (int q = 0; q < 8; q++) o8[q] = f2bf(acc[q] * inv);
        *(ushort8v*)(hb + (size_t)n * DHID + lc * 8) = o8;
    }
}

// ================= kF: GEMM2 =================
__global__ __launch_bounds__(256) void gemm2(const ushort* __restrict__ hb,
                                             const ushort* __restrict__ fcWt,
                                             const float* __restrict__ fcb,
                                             float* __restrict__ out) {
    __shared__ ushort Hs[128 * 128];   // 32 KB
    __shared__ ushort Fs[64 * 128];    // 16 KB
    const int t = threadIdx.x;
    const int row0 = blockIdx.x * 128;

    {
#pragma unroll
        for (int i = 0; i < 8; i++) {
            int u = i * 256 + t;
            int row = u >> 4;
            int grow = row0 + row;
            uint4 v = make_uint4(0, 0, 0, 0);
            if (grow < NN) v = *(const uint4*)(hb + (size_t)grow * 128 + (u & 15) * 8);
            int byte_off = row * 256 + (((u & 15) * 16) ^ ((row & 7) << 4));
            *(uint4*)((char*)Hs + byte_off) = v;
        }
#pragma unroll
        for (int i = 0; i < 4; i++) {
            int u = i * 256 + t;
            int n = u >> 4;
            int byte_off = n * 256 + (((u & 15) * 16) ^ ((n & 7) << 4));
            *(uint4*)((char*)Fs + byte_off) = ((const uint4*)fcWt)[u];
        }
    }

    const int w = t >> 6, lane = t & 63;
    const int rbase = w * 32;
    const int lcol = lane & 15;
    const int kgrp = (lane >> 4) * 16;

    f32x4 acc[2][4];
#pragma unroll
    for (int c = 0; c < 4; c++) {
        float bias = fcb[c * 16 + lcol];
#pragma unroll
        for (int r = 0; r < 2; r++)
#pragma unroll
            for (int i = 0; i < 4; i++) acc[r][c][i] = bias;
    }
    __syncthreads();

#pragma unroll
    for (int k0 = 0; k0 < 4; k0++) {
        int kbyte = k0 * 64 + kgrp;
        bf16x8 a[2], b[4];
#pragma unroll
        for (int r = 0; r < 2; r++) {
            int row = rbase + r * 16 + lcol;
            a[r] = *(bf16x8*)((char*)Hs + row * 256 + (kbyte ^ ((row & 7) << 4)));
        }
#pragma unroll
        for (int c = 0; c < 4; c++) {
            int n = c * 16 + lcol;
            b[c] = *(bf16x8*)((char*)Fs + n * 256 + (kbyte ^ ((n & 7) << 4)));
        }
#pragma unroll
        for (int r = 0; r < 2; r++)
#pragma unroll
            for (int c = 0; c < 4; c++)
                acc[r][c] = __builtin_amdgcn_mfma_f32_16x16x32_bf16(a[r], b[c], acc[r][c], 0, 0, 0);
    }

#pragma unroll
    for (int r = 0; r < 2; r++)
#pragma unroll
        for (int i = 0; i < 4; i++) {
            int row = rbase + r * 16 + (lane >> 4) * 4 + i;
            int grow = row0 + row;
            if (grow < NN) {
                float* op = out + (size_t)grow * 64 + lcol;
#pragma unroll
                for (int c = 0; c < 4; c++) op[c * 16] = acc[r][c][i];
            }
        }
}

// ---------------- launch ----------------
extern "C" void kernel_launch(void* const* d_in, const int* in_sizes, int n_in,
                              void* d_out, int out_size, void* d_ws, size_t ws_size,
                              hipStream_t stream) {
    const float* X      = (const float*)d_in[0];
    const float* W      = (const float*)d_in[1];
    const float* attn_l = (const float*)d_in[2];
    const float* attn_r = (const float*)d_in[3];
    const float* fcW    = (const float*)d_in[4];
    const float* fcb    = (const float*)d_in[5];
    const int*   src    = (const int*)d_in[6];
    const int*   dst    = (const int*)d_in[7];
    float* out = (float*)d_out;

    char* ws = (char*)d_ws;
    ushort* featb = (ushort*)ws;            ws += (size_t)NN * DHID * 2;
    ushort* hb    = (ushort*)ws;            ws += (size_t)NN * DHID * 2;
    ushort* Wt    = (ushort*)ws;            ws += (size_t)DHID * DIN * 2;
    ushort* fcWt  = (ushort*)ws;            ws += (size_t)NCLS * DHID * 2;
    float* el     = (float*)ws;             ws += (size_t)NN * 4;
    float* er     = (float*)ws;             ws += (size_t)NN * 4;
    int*   deg    = (int*)ws;               ws += (size_t)NN * 4;
    int*   off    = (int*)ws;               ws += (size_t)NN * 4;
    int*   ssrc   = (int*)ws;               ws += (size_t)NBUCK * ECAP * 4;
    unsigned* ebuf = (unsigned*)ws;         ws += (size_t)NBUCK * ECAP * 4;
    int*   gcur   = (int*)ws;               ws += (size_t)256 * 4;
    int*   bpre   = (int*)ws;               ws += (size_t)256 * 4;

    // kA: weight prep + gcur zero
    k_prep<<<PREPB, 256, 0, stream>>>(W, fcW, Wt, fcWt, gcur);
    // kB: CSR binning ∪ gemm1(+el/er) — independent, co-resident
    fused_bin_gemm1<<<NCHB + G1, 256, 0, stream>>>(src, dst, gcur, ebuf,
                                                   X, Wt, attn_l, attn_r, featb, el, er);
    // kC: per-bucket CSR finalize ∪ bucket prefix
    fused_csr<<<NBUCK + 1, 256, 0, stream>>>(ebuf, gcur, off, deg, ssrc, bpre);
    // kE: aggregate (self-searching edge-balanced groups)
    aggregate<<<NGRP / 16, 256, 0, stream>>>(off, deg, ssrc, el, er, featb, hb, bpre);
    // kF: output GEMM
    gemm2<<<(NN + 127) / 128, 256, 0, stream>>>(hb, fcWt, fcb, out);
}